// Round 9
// baseline (1067.543 us; speedup 1.0000x reference)
//
#include <hip/hip_runtime.h>
#include <math.h>

#define B_   4
#define M_   80
#define TMEL 63
#define R_   120
#define S_   240
#define Q_   256
#define NB_  16
#define L_   15872

typedef float  f32x4  __attribute__((ext_vector_type(4)));
typedef short  bf16x8 __attribute__((ext_vector_type(8)));
typedef short  short4_t __attribute__((ext_vector_type(4)));
typedef int    intx4  __attribute__((ext_vector_type(4)));

__device__ __forceinline__ short f2bf(float x) {
  unsigned u = __builtin_bit_cast(unsigned, x);
  u += 0x7fffu + ((u >> 16) & 1u);
  return (short)(u >> 16);
}
__device__ __forceinline__ float bf2f(unsigned short s) {
  unsigned u = ((unsigned)s) << 16;
  return __builtin_bit_cast(float, u);
}
// 16B non-temporal load (streaming data: keep out of L2 so skips/condb stay)
__device__ __forceinline__ int4 ntload16(const short* p) {
  intx4 v = __builtin_nontemporal_load((const intx4*)p);
  return *(int4*)&v;
}

// ---------------------------------------------------------------------------
// melT[b][i][m] bf16  <-  mel[b][m][i] f32
// ---------------------------------------------------------------------------
__global__ __launch_bounds__(256) void prep_melT_kernel(
    const float* __restrict__ mel, short* __restrict__ melT)
{
  const int idx = blockIdx.x * 256 + threadIdx.x;
  if (idx >= B_ * TMEL * M_) return;
  const int m = idx % M_;
  const int i = (idx / M_) % TMEL;
  const int b = idx / (M_ * TMEL);
  melT[idx] = f2bf(mel[b * (M_ * TMEL) + m * TMEL + i]);
}

// ---------------------------------------------------------------------------
// Wup[phi][c][j*80+m] bf16
// ---------------------------------------------------------------------------
__global__ __launch_bounds__(256) void prep_wup_kernel(
    const float* __restrict__ w_up, short* __restrict__ Wup)
{
  __shared__ float T[M_][65];
  const int c  = blockIdx.x >> 4;
  const int j  = (blockIdx.x >> 2) & 3;
  const int fb = blockIdx.x & 3;
  for (int idx = threadIdx.x; idx < M_ * 64; idx += 256) {
    const int pl = idx & 63, m = idx >> 6;
    const int phi = fb * 64 + pl;
    const int dmin = (phi < 112) ? -1 : -2;
    const int dmax = (phi < 144) ? 1 : 0;
    const int delta = dmin + j;
    float v = 0.0f;
    if (delta <= dmax)
      v = w_up[m * (M_ * 800) + c * 800 + (400 + phi + 256 * delta)];
    T[m][pl] = v;
  }
  __syncthreads();
  for (int idx = threadIdx.x; idx < 64 * M_; idx += 256) {
    const int m = idx % M_, pl = idx / M_;
    const int phi = fb * 64 + pl;
    Wup[((size_t)phi * M_ + c) * 320 + j * 80 + m] = f2bf(T[m][pl]);
  }
}

// ---------------------------------------------------------------------------
// Upsample as per-phase MFMA GEMM -> condb[b][t][80] bf16
// ---------------------------------------------------------------------------
#define KPU 328

__global__ __launch_bounds__(256, 2) void upsample_mfma_kernel(
    const short* __restrict__ melT, const short* __restrict__ Wup,
    const float* __restrict__ b_up, short* __restrict__ condb)
{
  __shared__ __align__(16) short Xu[64 * KPU];
  const int tid = threadIdx.x;
  const int phi = blockIdx.x;
  const int r0 = blockIdx.y * 64;
  const int dmin = (phi < 112) ? -1 : -2;

  for (int idx = tid; idx < 2560; idx += 256) {
    const int v = idx % 10;
    const int j = (idx / 10) & 3;
    const int rl = idx / 40;
    const int rho = r0 + rl;
    const int b = rho / 62;
    const int n = rho - b * 62;
    const int i = n - (dmin + j);
    int4 val = make_int4(0, 0, 0, 0);
    if (b < B_ && i >= 0 && i < TMEL)
      val = *(const int4*)&melT[((size_t)b * TMEL + i) * M_ + v * 8];
    *(int4*)&Xu[rl * KPU + j * 80 + v * 8] = val;
  }
  __syncthreads();

  const int lane = tid & 63;
  const int wv = tid >> 6;
  const int col = lane & 15;
  const int quad = lane >> 4;
  const int kq = quad * 8;

  f32x4 acc[5];
#pragma unroll
  for (int i = 0; i < 5; ++i) acc[i] = (f32x4)(0.f);
#pragma unroll
  for (int ks = 0; ks < 10; ++ks) {
    bf16x8 a = *(const bf16x8*)&Xu[(wv * 16 + col) * KPU + ks * 32 + kq];
#pragma unroll
    for (int ct = 0; ct < 5; ++ct) {
      bf16x8 b = *(const bf16x8*)(Wup + ((size_t)phi * M_ + ct * 16 + col) * 320 + ks * 32 + kq);
      acc[ct] = __builtin_amdgcn_mfma_f32_16x16x32_bf16(a, b, acc[ct], 0, 0, 0);
    }
  }
#pragma unroll
  for (int ct = 0; ct < 5; ++ct) {
    const int c = ct * 16 + col;
    const float bc = b_up[c];
#pragma unroll
    for (int reg = 0; reg < 4; ++reg) {
      const int rho = r0 + wv * 16 + quad * 4 + reg;
      if (rho < 248) {
        const int b = rho / 62;
        const int n = rho - b * 62;
        const int t = phi + (n << 8);
        condb[((size_t)b * L_ + t) * M_ + c] = f2bf(acc[ct][reg] + bc);
      }
    }
  }
}

// ---------------------------------------------------------------------------
// Weight prepacks. W1p: f-channels cp 0..119 (tiles 0-7), g cp 128..247
// (tiles 8-15) -> in-lane gating. W2p[i][384][128]: sp<240 = Wsk,
// sp 240..359 = Wres.
// ---------------------------------------------------------------------------
__global__ __launch_bounds__(256) void prepack_w1_kernel(
    const float* __restrict__ wg, const float* __restrict__ wc,
    short* __restrict__ W1p)
{
  const int idx = blockIdx.x * 256 + threadIdx.x;   // 16*256*320
  const int k = idx % 320;
  const int cp = (idx / 320) % 256;
  const int i = idx / (320 * 256);
  int corig = -1;
  if (cp < 128) { if (cp < 120) corig = cp; }
  else          { const int c = cp - 128; if (c < 120) corig = 120 + c; }
  float val = 0.0f;
  if (corig >= 0) {
    if (k < 120)      val = wg[((size_t)(i * 240 + corig) * 120 + k) * 2 + 0];
    else if (k < 240) val = wg[((size_t)(i * 240 + corig) * 120 + (k - 120)) * 2 + 1];
    else              val = wc[(size_t)(i * 240 + corig) * 80 + (k - 240)];
  }
  W1p[idx] = f2bf(val);
}

__global__ __launch_bounds__(256) void prepack_w2_kernel(
    const float* __restrict__ wsk, const float* __restrict__ wr,
    short* __restrict__ W2p)
{
  const int idx = blockIdx.x * 256 + threadIdx.x;   // 16*384*128
  const int k = idx % 128;
  const int sp = (idx / 128) % 384;
  const int i = idx / (128 * 384);
  float val = 0.0f;
  if (k < 120) {
    if (sp < 240)      val = wsk[(size_t)(i * 240 + sp) * 120 + k];
    else if (sp < 360) val = wr[(size_t)(i * 120 + (sp - 240)) * 120 + k];
  }
  W2p[idx] = f2bf(val);
}

__global__ __launch_bounds__(256) void prepack_rest_kernel(
    const float* __restrict__ wh1, const float* __restrict__ wh2,
    const float* __restrict__ bg, const float* __restrict__ bc,
    const float* __restrict__ bs, const float* __restrict__ br,
    short* __restrict__ Wh1p, short* __restrict__ Wh2p,
    float* __restrict__ bias1p, float* __restrict__ bias2p)
{
  const int idx = blockIdx.x * 256 + threadIdx.x;   // 141312
  if (idx < 65536) {
    const int q = idx >> 8, k = idx & 255;
    Wh1p[idx] = f2bf(k < 240 ? wh1[q * 240 + k] : 0.0f);
  } else if (idx < 131072) {
    Wh2p[idx - 65536] = f2bf(wh2[idx - 65536]);
  } else if (idx < 135168) {
    const int j = idx - 131072;
    const int i = j >> 8, cp = j & 255;
    float v = 0.0f;
    if (cp < 128) { if (cp < 120) v = bg[i * 240 + cp] + bc[i * 240 + cp]; }
    else { const int c = cp - 128; if (c < 120) v = bg[i * 240 + 120 + c] + bc[i * 240 + 120 + c]; }
    bias1p[j] = v;
  } else if (idx < 141312) {
    const int j = idx - 135168;
    const int i = j / 384, sp = j % 384;
    float v = 0.0f;
    if (sp < 240)      v = bs[i * 240 + sp];
    else if (sp < 360) v = br[i * 120 + (sp - 240)];
    bias2p[j] = v;
  }
}

#define KP1 320
#define SGP 248
#define SGP2 264
#define NTILE (L_ / 64)          // 248
#define NWG   (NTILE * B_)       // 992 -> bijective chunked swz (992%8==0)
#define CPX   (NWG / 8)          // 124

__device__ __forceinline__ int xswz(int row, int k) {
  return row * KP1 + (k ^ ((row & 7) << 3));
}

// ---------------------------------------------------------------------------
// Layers 0..14. R9 changes vs R8:
//  - in_conv FUSED into layer-0 staging (first=1, d=1): res values computed
//    on the fly from wav (w_in/b_in are 120 floats, L1-resident). Deletes the
//    in_conv dispatch + its 31 MB of traffic. Bit-identical f2bf path.
//  - res_in staging loads + res_out stores NON-TEMPORAL: res streams once
//    per layer; keeping it out of L2 leaves room for skips (3.8 MB/XCD
//    slice) + condb (1.27 MB) which ARE reused every layer.
// ---------------------------------------------------------------------------
__global__ __launch_bounds__(512, 4) void block_mfma_kernel(
    const short* __restrict__ res_in, short* __restrict__ res_out,
    unsigned short* __restrict__ skips, const short* __restrict__ condb,
    const float* __restrict__ wav, const float* __restrict__ w_in,
    const float* __restrict__ b_in,
    const short* __restrict__ W1, const short* __restrict__ W2,
    const float* __restrict__ bias1, const float* __restrict__ bias2,
    const int d, const int first)
{
  __shared__ __align__(16) short Xs[64 * KP1];

  const int tid = threadIdx.x;
  const int w_id = blockIdx.y * NTILE + blockIdx.x;
  const int nid  = (w_id & 7) * CPX + (w_id >> 3);
  const int bb   = nid / NTILE;
  const int t0   = (nid - bb * NTILE) * 64;

  {
    const int dd = (d <= 64) ? d : 64;
    const int nr = 64 + dd;
    for (int idx = tid; idx < nr * 15; idx += 512) {
      const int rr = idx / 15, c8 = idx - rr * 15;
      int ts;
      if (d <= 64)      ts = t0 - d + rr;
      else              ts = (rr < 64) ? (t0 - 128 + rr) : (t0 + rr - 64);
      int4 v = make_int4(0, 0, 0, 0);
      if (ts >= 0) {
        if (first) {
          // fused in_conv: res[ts][c] = w_in[c]*wav[ts] + b_in[c]
          const float wvv = wav[(size_t)bb * L_ + ts];
          unsigned short u[8];
#pragma unroll
          for (int e = 0; e < 8; ++e)
            u[e] = (unsigned short)f2bf(w_in[c8 * 8 + e] * wvv + b_in[c8 * 8 + e]);
          int* vi = (int*)&v;
#pragma unroll
          for (int m = 0; m < 4; ++m)
            vi[m] = (int)((unsigned)u[2 * m] | ((unsigned)u[2 * m + 1] << 16));
        } else {
          v = ntload16(res_in + ((size_t)(bb * L_ + ts) * 128 + c8 * 8));
        }
      }
      if (rr < 64)
        *(int4*)&Xs[xswz(rr, c8 * 8)] = v;
      const int r1 = rr - dd;
      if (r1 >= 0)
        *(int4*)&Xs[xswz(r1, 120 + c8 * 8)] = v;
    }
  }
  for (int idx = tid; idx < 640; idx += 512) {
    const int c = idx % 10, trw = idx / 10;
    const int4 v = *(const int4*)(condb + ((size_t)(bb * L_ + t0 + trw) * M_ + c * 8));
    *(int4*)&Xs[xswz(trw, 240 + c * 8)] = v;
  }
  __syncthreads();

  const int lane = tid & 63;
  const int wv = tid >> 6;
  const int col = lane & 15;
  const int quad = lane >> 4;
  const int kq = quad * 8;

  f32x4 acc[4][2];
#pragma unroll
  for (int a = 0; a < 4; ++a)
#pragma unroll
    for (int b = 0; b < 2; ++b) acc[a][b] = (f32x4)(0.f);
  __builtin_amdgcn_s_setprio(1);
#pragma unroll
  for (int ks = 0; ks < 10; ++ks) {
    bf16x8 av[4];
#pragma unroll
    for (int tf = 0; tf < 4; ++tf)
      av[tf] = *(const bf16x8*)&Xs[xswz(tf * 16 + col, ks * 32 + kq)];
#pragma unroll
    for (int ct = 0; ct < 2; ++ct) {
      const int cpt = ((ct == 0) ? wv : (wv + 8)) * 16 + col;
      bf16x8 b = *(const bf16x8*)(W1 + cpt * 320 + ks * 32 + kq);
#pragma unroll
      for (int tf = 0; tf < 4; ++tf)
        acc[tf][ct] = __builtin_amdgcn_mfma_f32_16x16x32_bf16(av[tf], b, acc[tf][ct], 0, 0, 0);
    }
  }
  __builtin_amdgcn_s_setprio(0);
  __syncthreads();

  {
    const int ch = wv * 16 + col;
    if (ch < 120) {
      const float bf_ = bias1[ch];
      const float bg_ = bias1[128 + ch];
#pragma unroll
      for (int tf = 0; tf < 4; ++tf) {
#pragma unroll
        for (int reg = 0; reg < 4; ++reg) {
          float f = acc[tf][0][reg] + bf_;
          float g = acc[tf][1][reg] + bg_;
          f = fminf(fmaxf(f, -15.f), 15.f);
          g = fminf(fmaxf(g, -15.f), 15.f);
          const float ef = __expf(2.0f * f);
          const float th = (ef - 1.0f) * __builtin_amdgcn_rcpf(ef + 1.0f);
          const float eg = __expf(-g);
          const float sg = __builtin_amdgcn_rcpf(1.0f + eg);
          const int t = tf * 16 + quad * 4 + reg;
          Xs[xswz(t, ch)] = f2bf(th * sg);
        }
      }
    }
  }
  if (tid < 64)
    *(int4*)&Xs[xswz(tid, 240)] = make_int4(0, 0, 0, 0);
  __syncthreads();

  const size_t srow = ((size_t)bb * L_ + t0) * 240;
  int4 sk0 = make_int4(0,0,0,0), sk1 = sk0, sk2 = sk0, sk3 = sk0;
  if (!first) {
    { const int idx = tid;        const int row = idx / 30, j = idx - row * 30;
      sk0 = *(const int4*)(skips + srow + row * 240 + j * 8); }
    { const int idx = tid + 512;  const int row = idx / 30, j = idx - row * 30;
      sk1 = *(const int4*)(skips + srow + row * 240 + j * 8); }
    { const int idx = tid + 1024; const int row = idx / 30, j = idx - row * 30;
      sk2 = *(const int4*)(skips + srow + row * 240 + j * 8); }
    if (tid + 1536 < 1920) {
      const int idx = tid + 1536; const int row = idx / 30, j = idx - row * 30;
      sk3 = *(const int4*)(skips + srow + row * 240 + j * 8); }
  }

  f32x4 acc2[4][3];
#pragma unroll
  for (int a = 0; a < 4; ++a)
#pragma unroll
    for (int b = 0; b < 3; ++b) acc2[a][b] = (f32x4)(0.f);
  __builtin_amdgcn_s_setprio(1);
#pragma unroll
  for (int ks = 0; ks < 4; ++ks) {
    const int ko = ks * 32 + kq;
    const int kz = (ko >= 120) ? (ko + 120) : ko;
    bf16x8 av[4];
#pragma unroll
    for (int tf = 0; tf < 4; ++tf)
      av[tf] = *(const bf16x8*)&Xs[xswz(tf * 16 + col, kz)];
#pragma unroll
    for (int st = 0; st < 3; ++st) {
      bf16x8 b = *(const bf16x8*)(W2 + ((wv * 3 + st) * 16 + col) * 128 + ks * 32 + kq);
#pragma unroll
      for (int tf = 0; tf < 4; ++tf)
        acc2[tf][st] = __builtin_amdgcn_mfma_f32_16x16x32_bf16(av[tf], b, acc2[tf][st], 0, 0, 0);
    }
  }
  __builtin_amdgcn_s_setprio(0);

  if (wv >= 5) {
#pragma unroll
    for (int st = 0; st < 3; ++st) {
      const int tile = wv * 3 + st;
      if (tile < 23) {
        const int s = tile * 16 + col;
        const int r = s - 240;
        if (r < 120) {
          const float b2 = bias2[s];
#pragma unroll
          for (int tf = 0; tf < 4; ++tf) {
#pragma unroll
            for (int reg = 0; reg < 4; ++reg) {
              const int t = tf * 16 + quad * 4 + reg;
              const float old = bf2f((unsigned short)Xs[xswz(t, 120 + r)]);
              __builtin_nontemporal_store(
                  f2bf(old + acc2[tf][st][reg] + b2),
                  res_out + ((size_t)(bb * L_ + t0 + t)) * 128 + r);
            }
          }
        }
      }
    }
  }
  __syncthreads();

  short* SG = Xs;
  if (wv < 5) {
#pragma unroll
    for (int st = 0; st < 3; ++st) {
      const int tile = wv * 3 + st;
      const int s = tile * 16 + col;
      const float b2 = bias2[s];
#pragma unroll
      for (int tf = 0; tf < 4; ++tf)
#pragma unroll
        for (int reg = 0; reg < 4; ++reg)
          SG[(tf * 16 + quad * 4 + reg) * SGP + s] = f2bf(acc2[tf][st][reg] + b2);
    }
  }
  __syncthreads();

#pragma unroll
  for (int it = 0; it < 4; ++it) {
    const int idx = tid + it * 512;
    if (idx < 1920) {
      const int row = idx / 30;
      const int j = idx - row * 30;
      unsigned short* gp = skips + srow + row * 240 + j * 8;
      int4 sv = *(const int4*)&SG[row * SGP + j * 8];
      const unsigned short* svp = (const unsigned short*)&sv;
      float vals[8];
#pragma unroll
      for (int e = 0; e < 8; ++e) vals[e] = bf2f(svp[e]);
      if (!first) {
        const int4 ov = (it == 0) ? sk0 : (it == 1) ? sk1 : (it == 2) ? sk2 : sk3;
        const unsigned short* ovp = (const unsigned short*)&ov;
#pragma unroll
        for (int e = 0; e < 8; ++e) vals[e] += bf2f(ovp[e]);
      }
      int4 res;
      unsigned short* rp = (unsigned short*)&res;
#pragma unroll
      for (int e = 0; e < 8; ++e) rp[e] = (unsigned short)f2bf(vals[e]);
      *(int4*)gp = res;
    }
  }
}

// ---------------------------------------------------------------------------
// LAYER 15 + HEAD fused (R8-proven). R9: staging load non-temporal.
// ---------------------------------------------------------------------------
__global__ __launch_bounds__(512, 4) void block_mfma_last_kernel(
    const short* __restrict__ res_in,
    const unsigned short* __restrict__ skips, const short* __restrict__ condb,
    const short* __restrict__ W1, const short* __restrict__ W2,
    const float* __restrict__ bias1, const float* __restrict__ bias2,
    const short* __restrict__ Wh1, const short* __restrict__ Wh2,
    const float* __restrict__ bh1, const float* __restrict__ bh2,
    float* __restrict__ out)
{
  __shared__ __align__(16) short Xs[64 * KP1];   // 40960 B; SG/Sh overlay

  const int tid = threadIdx.x;
  const int w_id = blockIdx.y * NTILE + blockIdx.x;
  const int nid  = (w_id & 7) * CPX + (w_id >> 3);
  const int bb   = nid / NTILE;
  const int t0   = (nid - bb * NTILE) * 64;

  // ---- stage (d = 128): two tap windows ----
  for (int idx = tid; idx < 128 * 15; idx += 512) {
    const int rr = idx / 15, c8 = idx - rr * 15;
    const int ts = (rr < 64) ? (t0 - 128 + rr) : (t0 + rr - 64);
    int4 v = make_int4(0, 0, 0, 0);
    if (ts >= 0)
      v = ntload16(res_in + ((size_t)(bb * L_ + ts) * 128 + c8 * 8));
    if (rr < 64)
      *(int4*)&Xs[xswz(rr, c8 * 8)] = v;                 // tap0
    const int r1 = rr - 64;
    if (r1 >= 0)
      *(int4*)&Xs[xswz(r1, 120 + c8 * 8)] = v;           // tap1
  }
  for (int idx = tid; idx < 640; idx += 512) {
    const int c = idx % 10, trw = idx / 10;
    const int4 v = *(const int4*)(condb + ((size_t)(bb * L_ + t0 + trw) * M_ + c * 8));
    *(int4*)&Xs[xswz(trw, 240 + c * 8)] = v;
  }
  __syncthreads();

  const int lane = tid & 63;
  const int wv = tid >> 6;
  const int col = lane & 15;
  const int quad = lane >> 4;
  const int kq = quad * 8;

  // ---- GEMM1 ----
  f32x4 acc[4][2];
#pragma unroll
  for (int a = 0; a < 4; ++a)
#pragma unroll
    for (int b = 0; b < 2; ++b) acc[a][b] = (f32x4)(0.f);
  __builtin_amdgcn_s_setprio(1);
#pragma unroll
  for (int ks = 0; ks < 10; ++ks) {
    bf16x8 av[4];
#pragma unroll
    for (int tf = 0; tf < 4; ++tf)
      av[tf] = *(const bf16x8*)&Xs[xswz(tf * 16 + col, ks * 32 + kq)];
#pragma unroll
    for (int ct = 0; ct < 2; ++ct) {
      const int cpt = ((ct == 0) ? wv : (wv + 8)) * 16 + col;
      bf16x8 b = *(const bf16x8*)(W1 + cpt * 320 + ks * 32 + kq);
#pragma unroll
      for (int tf = 0; tf < 4; ++tf)
        acc[tf][ct] = __builtin_amdgcn_mfma_f32_16x16x32_bf16(av[tf], b, acc[tf][ct], 0, 0, 0);
    }
  }
  __builtin_amdgcn_s_setprio(0);
  __syncthreads();

  // ---- gating -> Zs in tap0 bytes ----
  {
    const int ch = wv * 16 + col;
    if (ch < 120) {
      const float bf_ = bias1[ch];
      const float bg_ = bias1[128 + ch];
#pragma unroll
      for (int tf = 0; tf < 4; ++tf) {
#pragma unroll
        for (int reg = 0; reg < 4; ++reg) {
          float f = acc[tf][0][reg] + bf_;
          float g = acc[tf][1][reg] + bg_;
          f = fminf(fmaxf(f, -15.f), 15.f);
          g = fminf(fmaxf(g, -15.f), 15.f);
          const float ef = __expf(2.0f * f);
          const float th = (ef - 1.0f) * __builtin_amdgcn_rcpf(ef + 1.0f);
          const float eg = __expf(-g);
          const float sg = __builtin_amdgcn_rcpf(1.0f + eg);
          const int t = tf * 16 + quad * 4 + reg;
          Xs[xswz(t, ch)] = f2bf(th * sg);
        }
      }
    }
  }
  if (tid < 64)
    *(int4*)&Xs[xswz(tid, 240)] = make_int4(0, 0, 0, 0);
  __syncthreads();

  // ---- skips old-value prefetch ----
  const size_t srow = ((size_t)bb * L_ + t0) * 240;
  int4 sk0, sk1, sk2, sk3 = make_int4(0,0,0,0);
  { const int idx = tid;        const int row = idx / 30, j = idx - row * 30;
    sk0 = *(const int4*)(skips + srow + row * 240 + j * 8); }
  { const int idx = tid + 512;  const int row = idx / 30, j = idx - row * 30;
    sk1 = *(const int4*)(skips + srow + row * 240 + j * 8); }
  { const int idx = tid + 1024; const int row = idx / 30, j = idx - row * 30;
    sk2 = *(const int4*)(skips + srow + row * 240 + j * 8); }
  if (tid + 1536 < 1920) {
    const int idx = tid + 1536; const int row = idx / 30, j = idx - row * 30;
    sk3 = *(const int4*)(skips + srow + row * 240 + j * 8); }

  // ---- GEMM2: skip tiles only ----
  f32x4 acc2[4][2];
#pragma unroll
  for (int a = 0; a < 4; ++a)
#pragma unroll
    for (int b = 0; b < 2; ++b) acc2[a][b] = (f32x4)(0.f);
  __builtin_amdgcn_s_setprio(1);
#pragma unroll
  for (int ks = 0; ks < 4; ++ks) {
    const int ko = ks * 32 + kq;
    const int kz = (ko >= 120) ? (ko + 120) : ko;
    bf16x8 av[4];
#pragma unroll
    for (int tf = 0; tf < 4; ++tf)
      av[tf] = *(const bf16x8*)&Xs[xswz(tf * 16 + col, kz)];
#pragma unroll
    for (int st = 0; st < 2; ++st) {
      const int tile = wv * 2 + st;
      if (tile < 15) {
        bf16x8 b = *(const bf16x8*)(W2 + (tile * 16 + col) * 128 + ks * 32 + kq);
#pragma unroll
        for (int tf = 0; tf < 4; ++tf)
          acc2[tf][st] = __builtin_amdgcn_mfma_f32_16x16x32_bf16(av[tf], b, acc2[tf][st], 0, 0, 0);
      }
    }
  }
  __builtin_amdgcn_s_setprio(0);
  __syncthreads();   // all Zs reads done -> SG overlay legal

  // ---- SG stage at head stride (SGP2=264); zero pad cols 240..255 ----
  short* SG = Xs;
#pragma unroll
  for (int st = 0; st < 2; ++st) {
    const int tile = wv * 2 + st;
    if (tile < 15) {
      const int s = tile * 16 + col;
      const float b2 = bias2[s];
#pragma unroll
      for (int tf = 0; tf < 4; ++tf)
#pragma unroll
        for (int reg = 0; reg < 4; ++reg)
          SG[(tf * 16 + quad * 4 + reg) * SGP2 + s] = f2bf(acc2[tf][st][reg] + b2);
    }
  }
  if (tid < 128) {
    const int row = tid >> 1, g = tid & 1;
    *(int4*)&SG[row * SGP2 + 240 + g * 8] = make_int4(0, 0, 0, 0);
  }
  __syncthreads();

  // ---- in-place RMW + relu ----
#pragma unroll
  for (int it = 0; it < 4; ++it) {
    const int idx = tid + it * 512;
    if (idx < 1920) {
      const int row = idx / 30;
      const int j = idx - row * 30;
      short* lp = &SG[row * SGP2 + j * 8];
      int4 sv = *(const int4*)lp;
      const unsigned short* svp = (const unsigned short*)&sv;
      const int4 ov = (it == 0) ? sk0 : (it == 1) ? sk1 : (it == 2) ? sk2 : sk3;
      const unsigned short* ovp = (const unsigned short*)&ov;
      int4 res;
      unsigned short* rp = (unsigned short*)&res;
#pragma unroll
      for (int e = 0; e < 8; ++e)
        rp[e] = (unsigned short)f2bf(fmaxf(bf2f(svp[e]) + bf2f(ovp[e]), 0.0f));
      *(int4*)lp = res;
    }
  }
  __syncthreads();

  // ---- h1 GEMM (K=256) ----
  f32x4 acc1[4][2];
#pragma unroll
  for (int a = 0; a < 4; ++a)
#pragma unroll
    for (int b = 0; b < 2; ++b) acc1[a][b] = (f32x4)(0.f);
  __builtin_amdgcn_s_setprio(1);
#pragma unroll
  for (int ks = 0; ks < 8; ++ks) {
    bf16x8 av[4];
#pragma unroll
    for (int tf = 0; tf < 4; ++tf)
      av[tf] = *(const bf16x8*)&SG[(tf * 16 + col) * SGP2 + ks * 32 + kq];
#pragma unroll
    for (int ct = 0; ct < 2; ++ct) {
      bf16x8 b = *(const bf16x8*)(Wh1 + ((wv * 2 + ct) * 16 + col) * 256 + ks * 32 + kq);
#pragma unroll
      for (int tf = 0; tf < 4; ++tf)
        acc1[tf][ct] = __builtin_amdgcn_mfma_f32_16x16x32_bf16(av[tf], b, acc1[tf][ct], 0, 0, 0);
    }
  }
  __builtin_amdgcn_s_setprio(0);
  __syncthreads();   // SG reads done -> H overlay legal

#pragma unroll
  for (int ct = 0; ct < 2; ++ct) {
    const int q = (wv * 2 + ct) * 16 + col;
    const float b1 = bh1[q];
#pragma unroll
    for (int tf = 0; tf < 4; ++tf)
#pragma unroll
      for (int reg = 0; reg < 4; ++reg)
        SG[(tf * 16 + quad * 4 + reg) * SGP2 + q] = f2bf(fmaxf(acc1[tf][ct][reg] + b1, 0.0f));
  }
  __syncthreads();

  // ---- h2 GEMM (K=256) -> out ----
  f32x4 acc2h[4][2];
#pragma unroll
  for (int a = 0; a < 4; ++a)
#pragma unroll
    for (int b = 0; b < 2; ++b) acc2h[a][b] = (f32x4)(0.f);
  __builtin_amdgcn_s_setprio(1);
#pragma unroll
  for (int ks = 0; ks < 8; ++ks) {
    bf16x8 av[4];
#pragma unroll
    for (int tf = 0; tf < 4; ++tf)
      av[tf] = *(const bf16x8*)&SG[(tf * 16 + col) * SGP2 + ks * 32 + kq];
#pragma unroll
    for (int ct = 0; ct < 2; ++ct) {
      bf16x8 b = *(const bf16x8*)(Wh2 + ((wv * 2 + ct) * 16 + col) * 256 + ks * 32 + kq);
#pragma unroll
      for (int tf = 0; tf < 4; ++tf)
        acc2h[tf][ct] = __builtin_amdgcn_mfma_f32_16x16x32_bf16(av[tf], b, acc2h[tf][ct], 0, 0, 0);
    }
  }
  __builtin_amdgcn_s_setprio(0);
#pragma unroll
  for (int ct = 0; ct < 2; ++ct) {
    const int q = (wv * 2 + ct) * 16 + col;
    const float b2 = bh2[q];
#pragma unroll
    for (int tf = 0; tf < 4; ++tf) {
      const int tg0 = t0 + tf * 16 + quad * 4;
      float4 o = make_float4(acc2h[tf][ct][0] + b2, acc2h[tf][ct][1] + b2,
                             acc2h[tf][ct][2] + b2, acc2h[tf][ct][3] + b2);
      *(float4*)(out + ((size_t)(bb * Q_ + q)) * L_ + tg0) = o;
    }
  }
}

// ---------------------------------------------------------------------------
extern "C" void kernel_launch(void* const* d_in, const int* in_sizes, int n_in,
                              void* d_out, int out_size, void* d_ws, size_t ws_size,
                              hipStream_t stream) {
  const float* wav    = (const float*)d_in[0];
  const float* mel    = (const float*)d_in[1];
  const float* w_up   = (const float*)d_in[2];
  const float* b_up   = (const float*)d_in[3];
  const float* w_in   = (const float*)d_in[4];
  const float* b_in   = (const float*)d_in[5];
  const float* w_gate = (const float*)d_in[6];
  const float* b_gate = (const float*)d_in[7];
  const float* w_cond = (const float*)d_in[8];
  const float* b_cond = (const float*)d_in[9];
  const float* w_res  = (const float*)d_in[10];
  const float* b_res  = (const float*)d_in[11];
  const float* w_skip = (const float*)d_in[12];
  const float* b_skip = (const float*)d_in[13];
  const float* w_h1   = (const float*)d_in[14];
  const float* b_h1   = (const float*)d_in[15];
  const float* w_h2   = (const float*)d_in[16];
  const float* b_h2   = (const float*)d_in[17];
  float* out = (float*)d_out;

  char* w = (char*)d_ws;
  short* condb   = (short*)w;                 w += (size_t)B_ * L_ * M_ * 2;
  short* res0    = (short*)w;                 w += (size_t)B_ * L_ * 128 * 2;
  short* res1    = (short*)w;                 w += (size_t)B_ * L_ * 128 * 2;
  unsigned short* skips = (unsigned short*)w; w += (size_t)B_ * L_ * 240 * 2;
  short* W1p     = (short*)w;                 w += (size_t)16 * 256 * 320 * 2;
  short* W2p     = (short*)w;                 w += (size_t)16 * 384 * 128 * 2;
  short* Wh1p    = (short*)w;                 w += (size_t)256 * 256 * 2;
  short* Wh2p    = (short*)w;                 w += (size_t)256 * 256 * 2;
  float* bias1p  = (float*)w;                 w += (size_t)16 * 256 * 4;
  float* bias2p  = (float*)w;                 w += (size_t)16 * 384 * 4;
  short* melT    = (short*)w;                 w += (size_t)B_ * TMEL * M_ * 2;
  // Wup (13.1 MB) overlays skips: consumed before first block kernel.
  short* Wup = (short*)skips;

  prepack_w1_kernel<<<(16 * 256 * 320) / 256, 256, 0, stream>>>(w_gate, w_cond, W1p);
  prepack_w2_kernel<<<(16 * 384 * 128) / 256, 256, 0, stream>>>(w_skip, w_res, W2p);
  prepack_rest_kernel<<<141312 / 256, 256, 0, stream>>>(
      w_h1, w_h2, b_gate, b_cond, b_skip, b_res, Wh1p, Wh2p, bias1p, bias2p);
  prep_melT_kernel<<<(B_ * TMEL * M_ + 255) / 256, 256, 0, stream>>>(mel, melT);
  prep_wup_kernel<<<80 * 4 * 4, 256, 0, stream>>>(w_up, Wup);

  dim3 ugrid(256, 4);
  upsample_mfma_kernel<<<ugrid, 256, 0, stream>>>(melT, Wup, b_up, condb);

  dim3 bgrid(NTILE, B_);
  for (int i = 0; i < NB_ - 1; ++i) {
    const int d = 1 << (i & 7);
    const short* rin  = (i & 1) ? res1 : res0;   // layer 0: unused (from wav)
    short*       rout = (i & 1) ? res0 : res1;
    block_mfma_kernel<<<bgrid, 512, 0, stream>>>(
        rin, rout, skips, condb, wav, w_in, b_in,
        W1p + (size_t)i * 256 * 320, W2p + (size_t)i * 384 * 128,
        bias1p + i * 256, bias2p + i * 384,
        d, (i == 0) ? 1 : 0);
  }
  // layer 15 (d=128, reads res1) fused with head
  block_mfma_last_kernel<<<bgrid, 512, 0, stream>>>(
      res1, skips, condb,
      W1p + (size_t)15 * 256 * 320, W2p + (size_t)15 * 384 * 128,
      bias1p + 15 * 256, bias2p + 15 * 384,
      Wh1p, Wh2p, b_h1, b_h2, out);
}

// Round 10
// 982.130 us; speedup vs baseline: 1.0870x; 1.0870x over previous
//
#include <hip/hip_runtime.h>
#include <math.h>

#define B_   4
#define M_   80
#define TMEL 63
#define R_   120
#define S_   240
#define Q_   256
#define NB_  16
#define L_   15872

typedef float  f32x4  __attribute__((ext_vector_type(4)));
typedef short  bf16x8 __attribute__((ext_vector_type(8)));
typedef short  short4_t __attribute__((ext_vector_type(4)));

__device__ __forceinline__ short f2bf(float x) {
  unsigned u = __builtin_bit_cast(unsigned, x);
  u += 0x7fffu + ((u >> 16) & 1u);
  return (short)(u >> 16);
}
__device__ __forceinline__ float bf2f(unsigned short s) {
  unsigned u = ((unsigned)s) << 16;
  return __builtin_bit_cast(float, u);
}

// ---------------------------------------------------------------------------
// melT[b][i][m] bf16  <-  mel[b][m][i] f32
// ---------------------------------------------------------------------------
__global__ __launch_bounds__(256) void prep_melT_kernel(
    const float* __restrict__ mel, short* __restrict__ melT)
{
  const int idx = blockIdx.x * 256 + threadIdx.x;
  if (idx >= B_ * TMEL * M_) return;
  const int m = idx % M_;
  const int i = (idx / M_) % TMEL;
  const int b = idx / (M_ * TMEL);
  melT[idx] = f2bf(mel[b * (M_ * TMEL) + m * TMEL + i]);
}

// ---------------------------------------------------------------------------
// Wup[phi][c][j*80+m] bf16
// ---------------------------------------------------------------------------
__global__ __launch_bounds__(256) void prep_wup_kernel(
    const float* __restrict__ w_up, short* __restrict__ Wup)
{
  __shared__ float T[M_][65];
  const int c  = blockIdx.x >> 4;
  const int j  = (blockIdx.x >> 2) & 3;
  const int fb = blockIdx.x & 3;
  for (int idx = threadIdx.x; idx < M_ * 64; idx += 256) {
    const int pl = idx & 63, m = idx >> 6;
    const int phi = fb * 64 + pl;
    const int dmin = (phi < 112) ? -1 : -2;
    const int dmax = (phi < 144) ? 1 : 0;
    const int delta = dmin + j;
    float v = 0.0f;
    if (delta <= dmax)
      v = w_up[m * (M_ * 800) + c * 800 + (400 + phi + 256 * delta)];
    T[m][pl] = v;
  }
  __syncthreads();
  for (int idx = threadIdx.x; idx < 64 * M_; idx += 256) {
    const int m = idx % M_, pl = idx / M_;
    const int phi = fb * 64 + pl;
    Wup[((size_t)phi * M_ + c) * 320 + j * 80 + m] = f2bf(T[m][pl]);
  }
}

// ---------------------------------------------------------------------------
// Upsample as per-phase MFMA GEMM -> condb[b][t][80] bf16
// ---------------------------------------------------------------------------
#define KPU 328

__global__ __launch_bounds__(256, 2) void upsample_mfma_kernel(
    const short* __restrict__ melT, const short* __restrict__ Wup,
    const float* __restrict__ b_up, short* __restrict__ condb)
{
  __shared__ __align__(16) short Xu[64 * KPU];
  const int tid = threadIdx.x;
  const int phi = blockIdx.x;
  const int r0 = blockIdx.y * 64;
  const int dmin = (phi < 112) ? -1 : -2;

  for (int idx = tid; idx < 2560; idx += 256) {
    const int v = idx % 10;
    const int j = (idx / 10) & 3;
    const int rl = idx / 40;
    const int rho = r0 + rl;
    const int b = rho / 62;
    const int n = rho - b * 62;
    const int i = n - (dmin + j);
    int4 val = make_int4(0, 0, 0, 0);
    if (b < B_ && i >= 0 && i < TMEL)
      val = *(const int4*)&melT[((size_t)b * TMEL + i) * M_ + v * 8];
    *(int4*)&Xu[rl * KPU + j * 80 + v * 8] = val;
  }
  __syncthreads();

  const int lane = tid & 63;
  const int wv = tid >> 6;
  const int col = lane & 15;
  const int quad = lane >> 4;
  const int kq = quad * 8;

  f32x4 acc[5];
#pragma unroll
  for (int i = 0; i < 5; ++i) acc[i] = (f32x4)(0.f);
#pragma unroll
  for (int ks = 0; ks < 10; ++ks) {
    bf16x8 a = *(const bf16x8*)&Xu[(wv * 16 + col) * KPU + ks * 32 + kq];
#pragma unroll
    for (int ct = 0; ct < 5; ++ct) {
      bf16x8 b = *(const bf16x8*)(Wup + ((size_t)phi * M_ + ct * 16 + col) * 320 + ks * 32 + kq);
      acc[ct] = __builtin_amdgcn_mfma_f32_16x16x32_bf16(a, b, acc[ct], 0, 0, 0);
    }
  }
#pragma unroll
  for (int ct = 0; ct < 5; ++ct) {
    const int c = ct * 16 + col;
    const float bc = b_up[c];
#pragma unroll
    for (int reg = 0; reg < 4; ++reg) {
      const int rho = r0 + wv * 16 + quad * 4 + reg;
      if (rho < 248) {
        const int b = rho / 62;
        const int n = rho - b * 62;
        const int t = phi + (n << 8);
        condb[((size_t)b * L_ + t) * M_ + c] = f2bf(acc[ct][reg] + bc);
      }
    }
  }
}

// ---------------------------------------------------------------------------
// Weight prepacks. W1p: f-channels cp 0..119 (tiles 0-7), g cp 128..247
// (tiles 8-15) -> in-lane gating. W2p[i][384][128]: sp<240 = Wsk,
// sp 240..359 = Wres.
// ---------------------------------------------------------------------------
__global__ __launch_bounds__(256) void prepack_w1_kernel(
    const float* __restrict__ wg, const float* __restrict__ wc,
    short* __restrict__ W1p)
{
  const int idx = blockIdx.x * 256 + threadIdx.x;   // 16*256*320
  const int k = idx % 320;
  const int cp = (idx / 320) % 256;
  const int i = idx / (320 * 256);
  int corig = -1;
  if (cp < 128) { if (cp < 120) corig = cp; }
  else          { const int c = cp - 128; if (c < 120) corig = 120 + c; }
  float val = 0.0f;
  if (corig >= 0) {
    if (k < 120)      val = wg[((size_t)(i * 240 + corig) * 120 + k) * 2 + 0];
    else if (k < 240) val = wg[((size_t)(i * 240 + corig) * 120 + (k - 120)) * 2 + 1];
    else              val = wc[(size_t)(i * 240 + corig) * 80 + (k - 240)];
  }
  W1p[idx] = f2bf(val);
}

__global__ __launch_bounds__(256) void prepack_w2_kernel(
    const float* __restrict__ wsk, const float* __restrict__ wr,
    short* __restrict__ W2p)
{
  const int idx = blockIdx.x * 256 + threadIdx.x;   // 16*384*128
  const int k = idx % 128;
  const int sp = (idx / 128) % 384;
  const int i = idx / (128 * 384);
  float val = 0.0f;
  if (k < 120) {
    if (sp < 240)      val = wsk[(size_t)(i * 240 + sp) * 120 + k];
    else if (sp < 360) val = wr[(size_t)(i * 120 + (sp - 240)) * 120 + k];
  }
  W2p[idx] = f2bf(val);
}

__global__ __launch_bounds__(256) void prepack_rest_kernel(
    const float* __restrict__ wh1, const float* __restrict__ wh2,
    const float* __restrict__ bg, const float* __restrict__ bc,
    const float* __restrict__ bs, const float* __restrict__ br,
    short* __restrict__ Wh1p, short* __restrict__ Wh2p,
    float* __restrict__ bias1p, float* __restrict__ bias2p)
{
  const int idx = blockIdx.x * 256 + threadIdx.x;   // 141312
  if (idx < 65536) {
    const int q = idx >> 8, k = idx & 255;
    Wh1p[idx] = f2bf(k < 240 ? wh1[q * 240 + k] : 0.0f);
  } else if (idx < 131072) {
    Wh2p[idx - 65536] = f2bf(wh2[idx - 65536]);
  } else if (idx < 135168) {
    const int j = idx - 131072;
    const int i = j >> 8, cp = j & 255;
    float v = 0.0f;
    if (cp < 128) { if (cp < 120) v = bg[i * 240 + cp] + bc[i * 240 + cp]; }
    else { const int c = cp - 128; if (c < 120) v = bg[i * 240 + 120 + c] + bc[i * 240 + 120 + c]; }
    bias1p[j] = v;
  } else if (idx < 141312) {
    const int j = idx - 135168;
    const int i = j / 384, sp = j % 384;
    float v = 0.0f;
    if (sp < 240)      v = bs[i * 240 + sp];
    else if (sp < 360) v = br[i * 120 + (sp - 240)];
    bias2p[j] = v;
  }
}

#define KP1 320
#define SGP 248
#define SGP2 264
#define NTILE (L_ / 64)          // 248
#define NWG   (NTILE * B_)       // 992 -> bijective chunked swz (992%8==0)
#define CPX   (NWG / 8)          // 124

__device__ __forceinline__ int xswz(int row, int k) {
  return row * KP1 + (k ^ ((row & 7) << 3));
}

// ---------------------------------------------------------------------------
// Layers 0..14. R10 = R8-proven body + in_conv fused into layer-0 staging.
// R9 lesson (reverted): NON-TEMPORAL res loads/stores cost +73us wall —
// res is NOT stream-once: halo rows come from the neighbor tile's L2 lines
// and next layer's staging reads hit the L2 slice res_out just wrote.
// Keep plain int4 loads/stores.
// ---------------------------------------------------------------------------
__global__ __launch_bounds__(512, 4) void block_mfma_kernel(
    const short* __restrict__ res_in, short* __restrict__ res_out,
    unsigned short* __restrict__ skips, const short* __restrict__ condb,
    const float* __restrict__ wav, const float* __restrict__ w_in,
    const float* __restrict__ b_in,
    const short* __restrict__ W1, const short* __restrict__ W2,
    const float* __restrict__ bias1, const float* __restrict__ bias2,
    const int d, const int first)
{
  __shared__ __align__(16) short Xs[64 * KP1];

  const int tid = threadIdx.x;
  const int w_id = blockIdx.y * NTILE + blockIdx.x;
  const int nid  = (w_id & 7) * CPX + (w_id >> 3);
  const int bb   = nid / NTILE;
  const int t0   = (nid - bb * NTILE) * 64;

  {
    const int dd = (d <= 64) ? d : 64;
    const int nr = 64 + dd;
    for (int idx = tid; idx < nr * 15; idx += 512) {
      const int rr = idx / 15, c8 = idx - rr * 15;
      int ts;
      if (d <= 64)      ts = t0 - d + rr;
      else              ts = (rr < 64) ? (t0 - 128 + rr) : (t0 + rr - 64);
      int4 v = make_int4(0, 0, 0, 0);
      if (ts >= 0) {
        if (first) {
          // fused in_conv: res[ts][c] = w_in[c]*wav[ts] + b_in[c]
          const float wvv = wav[(size_t)bb * L_ + ts];
          unsigned short u[8];
#pragma unroll
          for (int e = 0; e < 8; ++e)
            u[e] = (unsigned short)f2bf(w_in[c8 * 8 + e] * wvv + b_in[c8 * 8 + e]);
          int* vi = (int*)&v;
#pragma unroll
          for (int m = 0; m < 4; ++m)
            vi[m] = (int)((unsigned)u[2 * m] | ((unsigned)u[2 * m + 1] << 16));
        } else {
          v = *(const int4*)(res_in + ((size_t)(bb * L_ + ts) * 128 + c8 * 8));
        }
      }
      if (rr < 64)
        *(int4*)&Xs[xswz(rr, c8 * 8)] = v;
      const int r1 = rr - dd;
      if (r1 >= 0)
        *(int4*)&Xs[xswz(r1, 120 + c8 * 8)] = v;
    }
  }
  for (int idx = tid; idx < 640; idx += 512) {
    const int c = idx % 10, trw = idx / 10;
    const int4 v = *(const int4*)(condb + ((size_t)(bb * L_ + t0 + trw) * M_ + c * 8));
    *(int4*)&Xs[xswz(trw, 240 + c * 8)] = v;
  }
  __syncthreads();

  const int lane = tid & 63;
  const int wv = tid >> 6;
  const int col = lane & 15;
  const int quad = lane >> 4;
  const int kq = quad * 8;

  f32x4 acc[4][2];
#pragma unroll
  for (int a = 0; a < 4; ++a)
#pragma unroll
    for (int b = 0; b < 2; ++b) acc[a][b] = (f32x4)(0.f);
  __builtin_amdgcn_s_setprio(1);
#pragma unroll
  for (int ks = 0; ks < 10; ++ks) {
    bf16x8 av[4];
#pragma unroll
    for (int tf = 0; tf < 4; ++tf)
      av[tf] = *(const bf16x8*)&Xs[xswz(tf * 16 + col, ks * 32 + kq)];
#pragma unroll
    for (int ct = 0; ct < 2; ++ct) {
      const int cpt = ((ct == 0) ? wv : (wv + 8)) * 16 + col;
      bf16x8 b = *(const bf16x8*)(W1 + cpt * 320 + ks * 32 + kq);
#pragma unroll
      for (int tf = 0; tf < 4; ++tf)
        acc[tf][ct] = __builtin_amdgcn_mfma_f32_16x16x32_bf16(av[tf], b, acc[tf][ct], 0, 0, 0);
    }
  }
  __builtin_amdgcn_s_setprio(0);
  __syncthreads();

  {
    const int ch = wv * 16 + col;
    if (ch < 120) {
      const float bf_ = bias1[ch];
      const float bg_ = bias1[128 + ch];
#pragma unroll
      for (int tf = 0; tf < 4; ++tf) {
#pragma unroll
        for (int reg = 0; reg < 4; ++reg) {
          float f = acc[tf][0][reg] + bf_;
          float g = acc[tf][1][reg] + bg_;
          f = fminf(fmaxf(f, -15.f), 15.f);
          g = fminf(fmaxf(g, -15.f), 15.f);
          const float ef = __expf(2.0f * f);
          const float th = (ef - 1.0f) * __builtin_amdgcn_rcpf(ef + 1.0f);
          const float eg = __expf(-g);
          const float sg = __builtin_amdgcn_rcpf(1.0f + eg);
          const int t = tf * 16 + quad * 4 + reg;
          Xs[xswz(t, ch)] = f2bf(th * sg);
        }
      }
    }
  }
  if (tid < 64)
    *(int4*)&Xs[xswz(tid, 240)] = make_int4(0, 0, 0, 0);
  __syncthreads();

  const size_t srow = ((size_t)bb * L_ + t0) * 240;
  int4 sk0 = make_int4(0,0,0,0), sk1 = sk0, sk2 = sk0, sk3 = sk0;
  if (!first) {
    { const int idx = tid;        const int row = idx / 30, j = idx - row * 30;
      sk0 = *(const int4*)(skips + srow + row * 240 + j * 8); }
    { const int idx = tid + 512;  const int row = idx / 30, j = idx - row * 30;
      sk1 = *(const int4*)(skips + srow + row * 240 + j * 8); }
    { const int idx = tid + 1024; const int row = idx / 30, j = idx - row * 30;
      sk2 = *(const int4*)(skips + srow + row * 240 + j * 8); }
    if (tid + 1536 < 1920) {
      const int idx = tid + 1536; const int row = idx / 30, j = idx - row * 30;
      sk3 = *(const int4*)(skips + srow + row * 240 + j * 8); }
  }

  f32x4 acc2[4][3];
#pragma unroll
  for (int a = 0; a < 4; ++a)
#pragma unroll
    for (int b = 0; b < 3; ++b) acc2[a][b] = (f32x4)(0.f);
  __builtin_amdgcn_s_setprio(1);
#pragma unroll
  for (int ks = 0; ks < 4; ++ks) {
    const int ko = ks * 32 + kq;
    const int kz = (ko >= 120) ? (ko + 120) : ko;
    bf16x8 av[4];
#pragma unroll
    for (int tf = 0; tf < 4; ++tf)
      av[tf] = *(const bf16x8*)&Xs[xswz(tf * 16 + col, kz)];
#pragma unroll
    for (int st = 0; st < 3; ++st) {
      bf16x8 b = *(const bf16x8*)(W2 + ((wv * 3 + st) * 16 + col) * 128 + ks * 32 + kq);
#pragma unroll
      for (int tf = 0; tf < 4; ++tf)
        acc2[tf][st] = __builtin_amdgcn_mfma_f32_16x16x32_bf16(av[tf], b, acc2[tf][st], 0, 0, 0);
    }
  }
  __builtin_amdgcn_s_setprio(0);

  if (wv >= 5) {
#pragma unroll
    for (int st = 0; st < 3; ++st) {
      const int tile = wv * 3 + st;
      if (tile < 23) {
        const int s = tile * 16 + col;
        const int r = s - 240;
        if (r < 120) {
          const float b2 = bias2[s];
#pragma unroll
          for (int tf = 0; tf < 4; ++tf) {
#pragma unroll
            for (int reg = 0; reg < 4; ++reg) {
              const int t = tf * 16 + quad * 4 + reg;
              const float old = bf2f((unsigned short)Xs[xswz(t, 120 + r)]);
              res_out[((size_t)(bb * L_ + t0 + t)) * 128 + r] =
                  f2bf(old + acc2[tf][st][reg] + b2);
            }
          }
        }
      }
    }
  }
  __syncthreads();

  short* SG = Xs;
  if (wv < 5) {
#pragma unroll
    for (int st = 0; st < 3; ++st) {
      const int tile = wv * 3 + st;
      const int s = tile * 16 + col;
      const float b2 = bias2[s];
#pragma unroll
      for (int tf = 0; tf < 4; ++tf)
#pragma unroll
        for (int reg = 0; reg < 4; ++reg)
          SG[(tf * 16 + quad * 4 + reg) * SGP + s] = f2bf(acc2[tf][st][reg] + b2);
    }
  }
  __syncthreads();

#pragma unroll
  for (int it = 0; it < 4; ++it) {
    const int idx = tid + it * 512;
    if (idx < 1920) {
      const int row = idx / 30;
      const int j = idx - row * 30;
      unsigned short* gp = skips + srow + row * 240 + j * 8;
      int4 sv = *(const int4*)&SG[row * SGP + j * 8];
      const unsigned short* svp = (const unsigned short*)&sv;
      float vals[8];
#pragma unroll
      for (int e = 0; e < 8; ++e) vals[e] = bf2f(svp[e]);
      if (!first) {
        const int4 ov = (it == 0) ? sk0 : (it == 1) ? sk1 : (it == 2) ? sk2 : sk3;
        const unsigned short* ovp = (const unsigned short*)&ov;
#pragma unroll
        for (int e = 0; e < 8; ++e) vals[e] += bf2f(ovp[e]);
      }
      int4 res;
      unsigned short* rp = (unsigned short*)&res;
#pragma unroll
      for (int e = 0; e < 8; ++e) rp[e] = (unsigned short)f2bf(vals[e]);
      *(int4*)gp = res;
    }
  }
}

// ---------------------------------------------------------------------------
// LAYER 15 + HEAD fused (R8-proven, plain loads).
// ---------------------------------------------------------------------------
__global__ __launch_bounds__(512, 4) void block_mfma_last_kernel(
    const short* __restrict__ res_in,
    const unsigned short* __restrict__ skips, const short* __restrict__ condb,
    const short* __restrict__ W1, const short* __restrict__ W2,
    const float* __restrict__ bias1, const float* __restrict__ bias2,
    const short* __restrict__ Wh1, const short* __restrict__ Wh2,
    const float* __restrict__ bh1, const float* __restrict__ bh2,
    float* __restrict__ out)
{
  __shared__ __align__(16) short Xs[64 * KP1];   // 40960 B; SG/Sh overlay

  const int tid = threadIdx.x;
  const int w_id = blockIdx.y * NTILE + blockIdx.x;
  const int nid  = (w_id & 7) * CPX + (w_id >> 3);
  const int bb   = nid / NTILE;
  const int t0   = (nid - bb * NTILE) * 64;

  // ---- stage (d = 128): two tap windows ----
  for (int idx = tid; idx < 128 * 15; idx += 512) {
    const int rr = idx / 15, c8 = idx - rr * 15;
    const int ts = (rr < 64) ? (t0 - 128 + rr) : (t0 + rr - 64);
    int4 v = make_int4(0, 0, 0, 0);
    if (ts >= 0)
      v = *(const int4*)(res_in + ((size_t)(bb * L_ + ts) * 128 + c8 * 8));
    if (rr < 64)
      *(int4*)&Xs[xswz(rr, c8 * 8)] = v;                 // tap0
    const int r1 = rr - 64;
    if (r1 >= 0)
      *(int4*)&Xs[xswz(r1, 120 + c8 * 8)] = v;           // tap1
  }
  for (int idx = tid; idx < 640; idx += 512) {
    const int c = idx % 10, trw = idx / 10;
    const int4 v = *(const int4*)(condb + ((size_t)(bb * L_ + t0 + trw) * M_ + c * 8));
    *(int4*)&Xs[xswz(trw, 240 + c * 8)] = v;
  }
  __syncthreads();

  const int lane = tid & 63;
  const int wv = tid >> 6;
  const int col = lane & 15;
  const int quad = lane >> 4;
  const int kq = quad * 8;

  // ---- GEMM1 ----
  f32x4 acc[4][2];
#pragma unroll
  for (int a = 0; a < 4; ++a)
#pragma unroll
    for (int b = 0; b < 2; ++b) acc[a][b] = (f32x4)(0.f);
  __builtin_amdgcn_s_setprio(1);
#pragma unroll
  for (int ks = 0; ks < 10; ++ks) {
    bf16x8 av[4];
#pragma unroll
    for (int tf = 0; tf < 4; ++tf)
      av[tf] = *(const bf16x8*)&Xs[xswz(tf * 16 + col, ks * 32 + kq)];
#pragma unroll
    for (int ct = 0; ct < 2; ++ct) {
      const int cpt = ((ct == 0) ? wv : (wv + 8)) * 16 + col;
      bf16x8 b = *(const bf16x8*)(W1 + cpt * 320 + ks * 32 + kq);
#pragma unroll
      for (int tf = 0; tf < 4; ++tf)
        acc[tf][ct] = __builtin_amdgcn_mfma_f32_16x16x32_bf16(av[tf], b, acc[tf][ct], 0, 0, 0);
    }
  }
  __builtin_amdgcn_s_setprio(0);
  __syncthreads();

  // ---- gating -> Zs in tap0 bytes ----
  {
    const int ch = wv * 16 + col;
    if (ch < 120) {
      const float bf_ = bias1[ch];
      const float bg_ = bias1[128 + ch];
#pragma unroll
      for (int tf = 0; tf < 4; ++tf) {
#pragma unroll
        for (int reg = 0; reg < 4; ++reg) {
          float f = acc[tf][0][reg] + bf_;
          float g = acc[tf][1][reg] + bg_;
          f = fminf(fmaxf(f, -15.f), 15.f);
          g = fminf(fmaxf(g, -15.f), 15.f);
          const float ef = __expf(2.0f * f);
          const float th = (ef - 1.0f) * __builtin_amdgcn_rcpf(ef + 1.0f);
          const float eg = __expf(-g);
          const float sg = __builtin_amdgcn_rcpf(1.0f + eg);
          const int t = tf * 16 + quad * 4 + reg;
          Xs[xswz(t, ch)] = f2bf(th * sg);
        }
      }
    }
  }
  if (tid < 64)
    *(int4*)&Xs[xswz(tid, 240)] = make_int4(0, 0, 0, 0);
  __syncthreads();

  // ---- skips old-value prefetch ----
  const size_t srow = ((size_t)bb * L_ + t0) * 240;
  int4 sk0, sk1, sk2, sk3 = make_int4(0,0,0,0);
  { const int idx = tid;        const int row = idx / 30, j = idx - row * 30;
    sk0 = *(const int4*)(skips + srow + row * 240 + j * 8); }
  { const int idx = tid + 512;  const int row = idx / 30, j = idx - row * 30;
    sk1 = *(const int4*)(skips + srow + row * 240 + j * 8); }
  { const int idx = tid + 1024; const int row = idx / 30, j = idx - row * 30;
    sk2 = *(const int4*)(skips + srow + row * 240 + j * 8); }
  if (tid + 1536 < 1920) {
    const int idx = tid + 1536; const int row = idx / 30, j = idx - row * 30;
    sk3 = *(const int4*)(skips + srow + row * 240 + j * 8); }

  // ---- GEMM2: skip tiles only ----
  f32x4 acc2[4][2];
#pragma unroll
  for (int a = 0; a < 4; ++a)
#pragma unroll
    for (int b = 0; b < 2; ++b) acc2[a][b] = (f32x4)(0.f);
  __builtin_amdgcn_s_setprio(1);
#pragma unroll
  for (int ks = 0; ks < 4; ++ks) {
    const int ko = ks * 32 + kq;
    const int kz = (ko >= 120) ? (ko + 120) : ko;
    bf16x8 av[4];
#pragma unroll
    for (int tf = 0; tf < 4; ++tf)
      av[tf] = *(const bf16x8*)&Xs[xswz(tf * 16 + col, kz)];
#pragma unroll
    for (int st = 0; st < 2; ++st) {
      const int tile = wv * 2 + st;
      if (tile < 15) {
        bf16x8 b = *(const bf16x8*)(W2 + (tile * 16 + col) * 128 + ks * 32 + kq);
#pragma unroll
        for (int tf = 0; tf < 4; ++tf)
          acc2[tf][st] = __builtin_amdgcn_mfma_f32_16x16x32_bf16(av[tf], b, acc2[tf][st], 0, 0, 0);
      }
    }
  }
  __builtin_amdgcn_s_setprio(0);
  __syncthreads();   // all Zs reads done -> SG overlay legal

  // ---- SG stage at head stride (SGP2=264); zero pad cols 240..255 ----
  short* SG = Xs;
#pragma unroll
  for (int st = 0; st < 2; ++st) {
    const int tile = wv * 2 + st;
    if (tile < 15) {
      const int s = tile * 16 + col;
      const float b2 = bias2[s];
#pragma unroll
      for (int tf = 0; tf < 4; ++tf)
#pragma unroll
        for (int reg = 0; reg < 4; ++reg)
          SG[(tf * 16 + quad * 4 + reg) * SGP2 + s] = f2bf(acc2[tf][st][reg] + b2);
    }
  }
  if (tid < 128) {
    const int row = tid >> 1, g = tid & 1;
    *(int4*)&SG[row * SGP2 + 240 + g * 8] = make_int4(0, 0, 0, 0);
  }
  __syncthreads();

  // ---- in-place RMW + relu ----
#pragma unroll
  for (int it = 0; it < 4; ++it) {
    const int idx = tid + it * 512;
    if (idx < 1920) {
      const int row = idx / 30;
      const int j = idx - row * 30;
      short* lp = &SG[row * SGP2 + j * 8];
      int4 sv = *(const int4*)lp;
      const unsigned short* svp = (const unsigned short*)&sv;
      const int4 ov = (it == 0) ? sk0 : (it == 1) ? sk1 : (it == 2) ? sk2 : sk3;
      const unsigned short* ovp = (const unsigned short*)&ov;
      int4 res;
      unsigned short* rp = (unsigned short*)&res;
#pragma unroll
      for (int e = 0; e < 8; ++e)
        rp[e] = (unsigned short)f2bf(fmaxf(bf2f(svp[e]) + bf2f(ovp[e]), 0.0f));
      *(int4*)lp = res;
    }
  }
  __syncthreads();

  // ---- h1 GEMM (K=256) ----
  f32x4 acc1[4][2];
#pragma unroll
  for (int a = 0; a < 4; ++a)
#pragma unroll
    for (int b = 0; b < 2; ++b) acc1[a][b] = (f32x4)(0.f);
  __builtin_amdgcn_s_setprio(1);
#pragma unroll
  for (int ks = 0; ks < 8; ++ks) {
    bf16x8 av[4];
#pragma unroll
    for (int tf = 0; tf < 4; ++tf)
      av[tf] = *(const bf16x8*)&SG[(tf * 16 + col) * SGP2 + ks * 32 + kq];
#pragma unroll
    for (int ct = 0; ct < 2; ++ct) {
      bf16x8 b = *(const bf16x8*)(Wh1 + ((wv * 2 + ct) * 16 + col) * 256 + ks * 32 + kq);
#pragma unroll
      for (int tf = 0; tf < 4; ++tf)
        acc1[tf][ct] = __builtin_amdgcn_mfma_f32_16x16x32_bf16(av[tf], b, acc1[tf][ct], 0, 0, 0);
    }
  }
  __builtin_amdgcn_s_setprio(0);
  __syncthreads();   // SG reads done -> H overlay legal

#pragma unroll
  for (int ct = 0; ct < 2; ++ct) {
    const int q = (wv * 2 + ct) * 16 + col;
    const float b1 = bh1[q];
#pragma unroll
    for (int tf = 0; tf < 4; ++tf)
#pragma unroll
      for (int reg = 0; reg < 4; ++reg)
        SG[(tf * 16 + quad * 4 + reg) * SGP2 + q] = f2bf(fmaxf(acc1[tf][ct][reg] + b1, 0.0f));
  }
  __syncthreads();

  // ---- h2 GEMM (K=256) -> out ----
  f32x4 acc2h[4][2];
#pragma unroll
  for (int a = 0; a < 4; ++a)
#pragma unroll
    for (int b = 0; b < 2; ++b) acc2h[a][b] = (f32x4)(0.f);
  __builtin_amdgcn_s_setprio(1);
#pragma unroll
  for (int ks = 0; ks < 8; ++ks) {
    bf16x8 av[4];
#pragma unroll
    for (int tf = 0; tf < 4; ++tf)
      av[tf] = *(const bf16x8*)&SG[(tf * 16 + col) * SGP2 + ks * 32 + kq];
#pragma unroll
    for (int ct = 0; ct < 2; ++ct) {
      bf16x8 b = *(const bf16x8*)(Wh2 + ((wv * 2 + ct) * 16 + col) * 256 + ks * 32 + kq);
#pragma unroll
      for (int tf = 0; tf < 4; ++tf)
        acc2h[tf][ct] = __builtin_amdgcn_mfma_f32_16x16x32_bf16(av[tf], b, acc2h[tf][ct], 0, 0, 0);
    }
  }
  __builtin_amdgcn_s_setprio(0);
#pragma unroll
  for (int ct = 0; ct < 2; ++ct) {
    const int q = (wv * 2 + ct) * 16 + col;
    const float b2 = bh2[q];
#pragma unroll
    for (int tf = 0; tf < 4; ++tf) {
      const int tg0 = t0 + tf * 16 + quad * 4;
      float4 o = make_float4(acc2h[tf][ct][0] + b2, acc2h[tf][ct][1] + b2,
                             acc2h[tf][ct][2] + b2, acc2h[tf][ct][3] + b2);
      *(float4*)(out + ((size_t)(bb * Q_ + q)) * L_ + tg0) = o;
    }
  }
}

// ---------------------------------------------------------------------------
extern "C" void kernel_launch(void* const* d_in, const int* in_sizes, int n_in,
                              void* d_out, int out_size, void* d_ws, size_t ws_size,
                              hipStream_t stream) {
  const float* wav    = (const float*)d_in[0];
  const float* mel    = (const float*)d_in[1];
  const float* w_up   = (const float*)d_in[2];
  const float* b_up   = (const float*)d_in[3];
  const float* w_in   = (const float*)d_in[4];
  const float* b_in   = (const float*)d_in[5];
  const float* w_gate = (const float*)d_in[6];
  const float* b_gate = (const float*)d_in[7];
  const float* w_cond = (const float*)d_in[8];
  const float* b_cond = (const float*)d_in[9];
  const float* w_res  = (const float*)d_in[10];
  const float* b_res  = (const float*)d_in[11];
  const float* w_skip = (const float*)d_in[12];
  const float* b_skip = (const float*)d_in[13];
  const float* w_h1   = (const float*)d_in[14];
  const float* b_h1   = (const float*)d_in[15];
  const float* w_h2   = (const float*)d_in[16];
  const float* b_h2   = (const float*)d_in[17];
  float* out = (float*)d_out;

  char* w = (char*)d_ws;
  short* condb   = (short*)w;                 w += (size_t)B_ * L_ * M_ * 2;
  short* res0    = (short*)w;                 w += (size_t)B_ * L_ * 128 * 2;
  short* res1    = (short*)w;                 w += (size_t)B_ * L_ * 128 * 2;
  unsigned short* skips = (unsigned short*)w; w += (size_t)B_ * L_ * 240 * 2;
  short* W1p     = (short*)w;                 w += (size_t)16 * 256 * 320 * 2;
  short* W2p     = (short*)w;                 w += (size_t)16 * 384 * 128 * 2;
  short* Wh1p    = (short*)w;                 w += (size_t)256 * 256 * 2;
  short* Wh2p    = (short*)w;                 w += (size_t)256 * 256 * 2;
  float* bias1p  = (float*)w;                 w += (size_t)16 * 256 * 4;
  float* bias2p  = (float*)w;                 w += (size_t)16 * 384 * 4;
  short* melT    = (short*)w;                 w += (size_t)B_ * TMEL * M_ * 2;
  // Wup (13.1 MB) overlays skips: consumed before first block kernel.
  short* Wup = (short*)skips;

  prepack_w1_kernel<<<(16 * 256 * 320) / 256, 256, 0, stream>>>(w_gate, w_cond, W1p);
  prepack_w2_kernel<<<(16 * 384 * 128) / 256, 256, 0, stream>>>(w_skip, w_res, W2p);
  prepack_rest_kernel<<<141312 / 256, 256, 0, stream>>>(
      w_h1, w_h2, b_gate, b_cond, b_skip, b_res, Wh1p, Wh2p, bias1p, bias2p);
  prep_melT_kernel<<<(B_ * TMEL * M_ + 255) / 256, 256, 0, stream>>>(mel, melT);
  prep_wup_kernel<<<80 * 4 * 4, 256, 0, stream>>>(w_up, Wup);

  dim3 ugrid(256, 4);
  upsample_mfma_kernel<<<ugrid, 256, 0, stream>>>(melT, Wup, b_up, condb);

  dim3 bgrid(NTILE, B_);
  for (int i = 0; i < NB_ - 1; ++i) {
    const int d = 1 << (i & 7);
    const short* rin  = (i & 1) ? res1 : res0;   // layer 0: unused (from wav)
    short*       rout = (i & 1) ? res0 : res1;
    block_mfma_kernel<<<bgrid, 512, 0, stream>>>(
        rin, rout, skips, condb, wav, w_in, b_in,
        W1p + (size_t)i * 256 * 320, W2p + (size_t)i * 384 * 128,
        bias1p + i * 256, bias2p + i * 384,
        d, (i == 0) ? 1 : 0);
  }
  // layer 15 (d=128, reads res1) fused with head
  block_mfma_last_kernel<<<bgrid, 512, 0, stream>>>(
      res1, skips, condb,
      W1p + (size_t)15 * 256 * 320, W2p + (size_t)15 * 384 * 128,
      bias1p + 15 * 256, bias2p + 15 * 384,
      Wh1p, Wh2p, b_h1, b_h2, out);
}

// Round 11
// 976.235 us; speedup vs baseline: 1.0935x; 1.0060x over previous
//
#include <hip/hip_runtime.h>
#include <math.h>

#define B_   4
#define M_   80
#define TMEL 63
#define R_   120
#define S_   240
#define Q_   256
#define NB_  16
#define L_   15872

typedef float  f32x4  __attribute__((ext_vector_type(4)));
typedef short  bf16x8 __attribute__((ext_vector_type(8)));
typedef short  short4_t __attribute__((ext_vector_type(4)));

__device__ __forceinline__ short f2bf(float x) {
  unsigned u = __builtin_bit_cast(unsigned, x);
  u += 0x7fffu + ((u >> 16) & 1u);
  return (short)(u >> 16);
}
__device__ __forceinline__ float bf2f(unsigned short s) {
  unsigned u = ((unsigned)s) << 16;
  return __builtin_bit_cast(float, u);
}

// ---------------------------------------------------------------------------
// Merged prepack kernel (R11): w1 | w2 | rest | melT | wup in one dispatch.
// Block ranges: [0,5120) w1, [5120,8192) w2, [8192,8744) rest,
// [8744,8823) melT, [8823,10103) wup. Saves 4 launch boundaries (~10us).
// ---------------------------------------------------------------------------
__global__ __launch_bounds__(256) void prep_all_kernel(
    const float* __restrict__ wg, const float* __restrict__ wc,
    const float* __restrict__ wsk, const float* __restrict__ wr,
    const float* __restrict__ wh1, const float* __restrict__ wh2,
    const float* __restrict__ bg, const float* __restrict__ bc,
    const float* __restrict__ bs, const float* __restrict__ br,
    const float* __restrict__ mel, const float* __restrict__ w_up,
    short* __restrict__ W1p, short* __restrict__ W2p,
    short* __restrict__ Wh1p, short* __restrict__ Wh2p,
    float* __restrict__ bias1p, float* __restrict__ bias2p,
    short* __restrict__ melT, short* __restrict__ Wup)
{
  __shared__ float T[M_][65];
  const int bid = blockIdx.x;
  const int tid = threadIdx.x;

  if (bid < 5120) {
    // ---- W1p: f-channels cp 0..119 (tiles 0-7), g cp 128..247 ----
    const int idx = bid * 256 + tid;
    const int k = idx % 320;
    const int cp = (idx / 320) % 256;
    const int i = idx / (320 * 256);
    int corig = -1;
    if (cp < 128) { if (cp < 120) corig = cp; }
    else          { const int c = cp - 128; if (c < 120) corig = 120 + c; }
    float val = 0.0f;
    if (corig >= 0) {
      if (k < 120)      val = wg[((size_t)(i * 240 + corig) * 120 + k) * 2 + 0];
      else if (k < 240) val = wg[((size_t)(i * 240 + corig) * 120 + (k - 120)) * 2 + 1];
      else              val = wc[(size_t)(i * 240 + corig) * 80 + (k - 240)];
    }
    W1p[idx] = f2bf(val);
  } else if (bid < 8192) {
    // ---- W2p: sp<240 = Wsk, sp 240..359 = Wres ----
    const int idx = (bid - 5120) * 256 + tid;
    const int k = idx % 128;
    const int sp = (idx / 128) % 384;
    const int i = idx / (128 * 384);
    float val = 0.0f;
    if (k < 120) {
      if (sp < 240)      val = wsk[(size_t)(i * 240 + sp) * 120 + k];
      else if (sp < 360) val = wr[(size_t)(i * 120 + (sp - 240)) * 120 + k];
    }
    W2p[idx] = f2bf(val);
  } else if (bid < 8744) {
    // ---- Wh1p / Wh2p / bias1p / bias2p ----
    const int idx = (bid - 8192) * 256 + tid;
    if (idx < 65536) {
      const int q = idx >> 8, k = idx & 255;
      Wh1p[idx] = f2bf(k < 240 ? wh1[q * 240 + k] : 0.0f);
    } else if (idx < 131072) {
      Wh2p[idx - 65536] = f2bf(wh2[idx - 65536]);
    } else if (idx < 135168) {
      const int j = idx - 131072;
      const int i = j >> 8, cp = j & 255;
      float v = 0.0f;
      if (cp < 128) { if (cp < 120) v = bg[i * 240 + cp] + bc[i * 240 + cp]; }
      else { const int c = cp - 128; if (c < 120) v = bg[i * 240 + 120 + c] + bc[i * 240 + 120 + c]; }
      bias1p[j] = v;
    } else if (idx < 141312) {
      const int j = idx - 135168;
      const int i = j / 384, sp = j % 384;
      float v = 0.0f;
      if (sp < 240)      v = bs[i * 240 + sp];
      else if (sp < 360) v = br[i * 120 + (sp - 240)];
      bias2p[j] = v;
    }
  } else if (bid < 8823) {
    // ---- melT[b][i][m] <- mel[b][m][i] ----
    const int idx = (bid - 8744) * 256 + tid;
    if (idx < B_ * TMEL * M_) {
      const int m = idx % M_;
      const int i = (idx / M_) % TMEL;
      const int b = idx / (M_ * TMEL);
      melT[idx] = f2bf(mel[b * (M_ * TMEL) + m * TMEL + i]);
    }
  } else {
    // ---- Wup ----
    const int wb = bid - 8823;
    const int c  = wb >> 4;
    const int j  = (wb >> 2) & 3;
    const int fb = wb & 3;
    for (int idx = tid; idx < M_ * 64; idx += 256) {
      const int pl = idx & 63, m = idx >> 6;
      const int phi = fb * 64 + pl;
      const int dmin = (phi < 112) ? -1 : -2;
      const int dmax = (phi < 144) ? 1 : 0;
      const int delta = dmin + j;
      float v = 0.0f;
      if (delta <= dmax)
        v = w_up[m * (M_ * 800) + c * 800 + (400 + phi + 256 * delta)];
      T[m][pl] = v;
    }
    __syncthreads();
    for (int idx = tid; idx < 64 * M_; idx += 256) {
      const int m = idx % M_, pl = idx / M_;
      const int phi = fb * 64 + pl;
      Wup[((size_t)phi * M_ + c) * 320 + j * 80 + m] = f2bf(T[m][pl]);
    }
  }
}

// ---------------------------------------------------------------------------
// Upsample as per-phase MFMA GEMM -> condb[b][t][80] bf16
// ---------------------------------------------------------------------------
#define KPU 328

__global__ __launch_bounds__(256, 2) void upsample_mfma_kernel(
    const short* __restrict__ melT, const short* __restrict__ Wup,
    const float* __restrict__ b_up, short* __restrict__ condb)
{
  __shared__ __align__(16) short Xu[64 * KPU];
  const int tid = threadIdx.x;
  const int phi = blockIdx.x;
  const int r0 = blockIdx.y * 64;
  const int dmin = (phi < 112) ? -1 : -2;

  for (int idx = tid; idx < 2560; idx += 256) {
    const int v = idx % 10;
    const int j = (idx / 10) & 3;
    const int rl = idx / 40;
    const int rho = r0 + rl;
    const int b = rho / 62;
    const int n = rho - b * 62;
    const int i = n - (dmin + j);
    int4 val = make_int4(0, 0, 0, 0);
    if (b < B_ && i >= 0 && i < TMEL)
      val = *(const int4*)&melT[((size_t)b * TMEL + i) * M_ + v * 8];
    *(int4*)&Xu[rl * KPU + j * 80 + v * 8] = val;
  }
  __syncthreads();

  const int lane = tid & 63;
  const int wv = tid >> 6;
  const int col = lane & 15;
  const int quad = lane >> 4;
  const int kq = quad * 8;

  f32x4 acc[5];
#pragma unroll
  for (int i = 0; i < 5; ++i) acc[i] = (f32x4)(0.f);
#pragma unroll
  for (int ks = 0; ks < 10; ++ks) {
    bf16x8 a = *(const bf16x8*)&Xu[(wv * 16 + col) * KPU + ks * 32 + kq];
#pragma unroll
    for (int ct = 0; ct < 5; ++ct) {
      bf16x8 b = *(const bf16x8*)(Wup + ((size_t)phi * M_ + ct * 16 + col) * 320 + ks * 32 + kq);
      acc[ct] = __builtin_amdgcn_mfma_f32_16x16x32_bf16(a, b, acc[ct], 0, 0, 0);
    }
  }
#pragma unroll
  for (int ct = 0; ct < 5; ++ct) {
    const int c = ct * 16 + col;
    const float bc = b_up[c];
#pragma unroll
    for (int reg = 0; reg < 4; ++reg) {
      const int rho = r0 + wv * 16 + quad * 4 + reg;
      if (rho < 248) {
        const int b = rho / 62;
        const int n = rho - b * 62;
        const int t = phi + (n << 8);
        condb[((size_t)b * L_ + t) * M_ + c] = f2bf(acc[ct][reg] + bc);
      }
    }
  }
}

#define KP1 320
#define SGP 248
#define SGP2 256
#define NTILE (L_ / 64)          // 248
#define NWG   (NTILE * B_)       // 992 -> bijective chunked swz (992%8==0)
#define CPX   (NWG / 8)          // 124

__device__ __forceinline__ int xswz(int row, int k) {
  return row * KP1 + (k ^ ((row & 7) << 3));
}
// R11: last-kernel SG/head buffer swizzle. SGP2=256 (512B/row == 0 mod 32
// banks) + the proven Xs XOR pattern -> b128 reads 2-way (free per m136).
__device__ __forceinline__ int sswz(int row, int k) {
  return row * SGP2 + (k ^ ((row & 7) << 3));
}

// ---------------------------------------------------------------------------
// Layers 0..14 (R10-proven, BIT-IDENTICAL: 64 VGPR = exactly the 4-WG/CU
// boundary; do not disturb register lifetimes).
// ---------------------------------------------------------------------------
__global__ __launch_bounds__(512, 4) void block_mfma_kernel(
    const short* __restrict__ res_in, short* __restrict__ res_out,
    unsigned short* __restrict__ skips, const short* __restrict__ condb,
    const float* __restrict__ wav, const float* __restrict__ w_in,
    const float* __restrict__ b_in,
    const short* __restrict__ W1, const short* __restrict__ W2,
    const float* __restrict__ bias1, const float* __restrict__ bias2,
    const int d, const int first)
{
  __shared__ __align__(16) short Xs[64 * KP1];

  const int tid = threadIdx.x;
  const int w_id = blockIdx.y * NTILE + blockIdx.x;
  const int nid  = (w_id & 7) * CPX + (w_id >> 3);
  const int bb   = nid / NTILE;
  const int t0   = (nid - bb * NTILE) * 64;

  {
    const int dd = (d <= 64) ? d : 64;
    const int nr = 64 + dd;
    for (int idx = tid; idx < nr * 15; idx += 512) {
      const int rr = idx / 15, c8 = idx - rr * 15;
      int ts;
      if (d <= 64)      ts = t0 - d + rr;
      else              ts = (rr < 64) ? (t0 - 128 + rr) : (t0 + rr - 64);
      int4 v = make_int4(0, 0, 0, 0);
      if (ts >= 0) {
        if (first) {
          // fused in_conv: res[ts][c] = w_in[c]*wav[ts] + b_in[c]
          const float wvv = wav[(size_t)bb * L_ + ts];
          unsigned short u[8];
#pragma unroll
          for (int e = 0; e < 8; ++e)
            u[e] = (unsigned short)f2bf(w_in[c8 * 8 + e] * wvv + b_in[c8 * 8 + e]);
          int* vi = (int*)&v;
#pragma unroll
          for (int m = 0; m < 4; ++m)
            vi[m] = (int)((unsigned)u[2 * m] | ((unsigned)u[2 * m + 1] << 16));
        } else {
          v = *(const int4*)(res_in + ((size_t)(bb * L_ + ts) * 128 + c8 * 8));
        }
      }
      if (rr < 64)
        *(int4*)&Xs[xswz(rr, c8 * 8)] = v;
      const int r1 = rr - dd;
      if (r1 >= 0)
        *(int4*)&Xs[xswz(r1, 120 + c8 * 8)] = v;
    }
  }
  for (int idx = tid; idx < 640; idx += 512) {
    const int c = idx % 10, trw = idx / 10;
    const int4 v = *(const int4*)(condb + ((size_t)(bb * L_ + t0 + trw) * M_ + c * 8));
    *(int4*)&Xs[xswz(trw, 240 + c * 8)] = v;
  }
  __syncthreads();

  const int lane = tid & 63;
  const int wv = tid >> 6;
  const int col = lane & 15;
  const int quad = lane >> 4;
  const int kq = quad * 8;

  f32x4 acc[4][2];
#pragma unroll
  for (int a = 0; a < 4; ++a)
#pragma unroll
    for (int b = 0; b < 2; ++b) acc[a][b] = (f32x4)(0.f);
  __builtin_amdgcn_s_setprio(1);
#pragma unroll
  for (int ks = 0; ks < 10; ++ks) {
    bf16x8 av[4];
#pragma unroll
    for (int tf = 0; tf < 4; ++tf)
      av[tf] = *(const bf16x8*)&Xs[xswz(tf * 16 + col, ks * 32 + kq)];
#pragma unroll
    for (int ct = 0; ct < 2; ++ct) {
      const int cpt = ((ct == 0) ? wv : (wv + 8)) * 16 + col;
      bf16x8 b = *(const bf16x8*)(W1 + cpt * 320 + ks * 32 + kq);
#pragma unroll
      for (int tf = 0; tf < 4; ++tf)
        acc[tf][ct] = __builtin_amdgcn_mfma_f32_16x16x32_bf16(av[tf], b, acc[tf][ct], 0, 0, 0);
    }
  }
  __builtin_amdgcn_s_setprio(0);
  __syncthreads();

  {
    const int ch = wv * 16 + col;
    if (ch < 120) {
      const float bf_ = bias1[ch];
      const float bg_ = bias1[128 + ch];
#pragma unroll
      for (int tf = 0; tf < 4; ++tf) {
#pragma unroll
        for (int reg = 0; reg < 4; ++reg) {
          float f = acc[tf][0][reg] + bf_;
          float g = acc[tf][1][reg] + bg_;
          f = fminf(fmaxf(f, -15.f), 15.f);
          g = fminf(fmaxf(g, -15.f), 15.f);
          const float ef = __expf(2.0f * f);
          const float th = (ef - 1.0f) * __builtin_amdgcn_rcpf(ef + 1.0f);
          const float eg = __expf(-g);
          const float sg = __builtin_amdgcn_rcpf(1.0f + eg);
          const int t = tf * 16 + quad * 4 + reg;
          Xs[xswz(t, ch)] = f2bf(th * sg);
        }
      }
    }
  }
  if (tid < 64)
    *(int4*)&Xs[xswz(tid, 240)] = make_int4(0, 0, 0, 0);
  __syncthreads();

  const size_t srow = ((size_t)bb * L_ + t0) * 240;
  int4 sk0 = make_int4(0,0,0,0), sk1 = sk0, sk2 = sk0, sk3 = sk0;
  if (!first) {
    { const int idx = tid;        const int row = idx / 30, j = idx - row * 30;
      sk0 = *(const int4*)(skips + srow + row * 240 + j * 8); }
    { const int idx = tid + 512;  const int row = idx / 30, j = idx - row * 30;
      sk1 = *(const int4*)(skips + srow + row * 240 + j * 8); }
    { const int idx = tid + 1024; const int row = idx / 30, j = idx - row * 30;
      sk2 = *(const int4*)(skips + srow + row * 240 + j * 8); }
    if (tid + 1536 < 1920) {
      const int idx = tid + 1536; const int row = idx / 30, j = idx - row * 30;
      sk3 = *(const int4*)(skips + srow + row * 240 + j * 8); }
  }

  f32x4 acc2[4][3];
#pragma unroll
  for (int a = 0; a < 4; ++a)
#pragma unroll
    for (int b = 0; b < 3; ++b) acc2[a][b] = (f32x4)(0.f);
  __builtin_amdgcn_s_setprio(1);
#pragma unroll
  for (int ks = 0; ks < 4; ++ks) {
    const int ko = ks * 32 + kq;
    const int kz = (ko >= 120) ? (ko + 120) : ko;
    bf16x8 av[4];
#pragma unroll
    for (int tf = 0; tf < 4; ++tf)
      av[tf] = *(const bf16x8*)&Xs[xswz(tf * 16 + col, kz)];
#pragma unroll
    for (int st = 0; st < 3; ++st) {
      bf16x8 b = *(const bf16x8*)(W2 + ((wv * 3 + st) * 16 + col) * 128 + ks * 32 + kq);
#pragma unroll
      for (int tf = 0; tf < 4; ++tf)
        acc2[tf][st] = __builtin_amdgcn_mfma_f32_16x16x32_bf16(av[tf], b, acc2[tf][st], 0, 0, 0);
    }
  }
  __builtin_amdgcn_s_setprio(0);

  if (wv >= 5) {
#pragma unroll
    for (int st = 0; st < 3; ++st) {
      const int tile = wv * 3 + st;
      if (tile < 23) {
        const int s = tile * 16 + col;
        const int r = s - 240;
        if (r < 120) {
          const float b2 = bias2[s];
#pragma unroll
          for (int tf = 0; tf < 4; ++tf) {
#pragma unroll
            for (int reg = 0; reg < 4; ++reg) {
              const int t = tf * 16 + quad * 4 + reg;
              const float old = bf2f((unsigned short)Xs[xswz(t, 120 + r)]);
              res_out[((size_t)(bb * L_ + t0 + t)) * 128 + r] =
                  f2bf(old + acc2[tf][st][reg] + b2);
            }
          }
        }
      }
    }
  }
  __syncthreads();

  short* SG = Xs;
  if (wv < 5) {
#pragma unroll
    for (int st = 0; st < 3; ++st) {
      const int tile = wv * 3 + st;
      const int s = tile * 16 + col;
      const float b2 = bias2[s];
#pragma unroll
      for (int tf = 0; tf < 4; ++tf)
#pragma unroll
        for (int reg = 0; reg < 4; ++reg)
          SG[(tf * 16 + quad * 4 + reg) * SGP + s] = f2bf(acc2[tf][st][reg] + b2);
    }
  }
  __syncthreads();

#pragma unroll
  for (int it = 0; it < 4; ++it) {
    const int idx = tid + it * 512;
    if (idx < 1920) {
      const int row = idx / 30;
      const int j = idx - row * 30;
      unsigned short* gp = skips + srow + row * 240 + j * 8;
      int4 sv = *(const int4*)&SG[row * SGP + j * 8];
      const unsigned short* svp = (const unsigned short*)&sv;
      float vals[8];
#pragma unroll
      for (int e = 0; e < 8; ++e) vals[e] = bf2f(svp[e]);
      if (!first) {
        const int4 ov = (it == 0) ? sk0 : (it == 1) ? sk1 : (it == 2) ? sk2 : sk3;
        const unsigned short* ovp = (const unsigned short*)&ov;
#pragma unroll
        for (int e = 0; e < 8; ++e) vals[e] += bf2f(ovp[e]);
      }
      int4 res;
      unsigned short* rp = (unsigned short*)&res;
#pragma unroll
      for (int e = 0; e < 8; ++e) rp[e] = (unsigned short)f2bf(vals[e]);
      *(int4*)gp = res;
    }
  }
}

// ---------------------------------------------------------------------------
// LAYER 15 + HEAD fused. R11: SG/head buffer SGP2 264->256 + XOR swizzle
// (sswz) on ALL SG accesses — fixes the 2.4M bank conflicts (vs 310K in
// block kernel) from the linear-stride LDS-RMW + head phases.
// ---------------------------------------------------------------------------
__global__ __launch_bounds__(512, 4) void block_mfma_last_kernel(
    const short* __restrict__ res_in,
    const unsigned short* __restrict__ skips, const short* __restrict__ condb,
    const short* __restrict__ W1, const short* __restrict__ W2,
    const float* __restrict__ bias1, const float* __restrict__ bias2,
    const short* __restrict__ Wh1, const short* __restrict__ Wh2,
    const float* __restrict__ bh1, const float* __restrict__ bh2,
    float* __restrict__ out)
{
  __shared__ __align__(16) short Xs[64 * KP1];   // 40960 B; SG overlay 32768 B

  const int tid = threadIdx.x;
  const int w_id = blockIdx.y * NTILE + blockIdx.x;
  const int nid  = (w_id & 7) * CPX + (w_id >> 3);
  const int bb   = nid / NTILE;
  const int t0   = (nid - bb * NTILE) * 64;

  // ---- stage (d = 128): two tap windows ----
  for (int idx = tid; idx < 128 * 15; idx += 512) {
    const int rr = idx / 15, c8 = idx - rr * 15;
    const int ts = (rr < 64) ? (t0 - 128 + rr) : (t0 + rr - 64);
    int4 v = make_int4(0, 0, 0, 0);
    if (ts >= 0)
      v = *(const int4*)(res_in + ((size_t)(bb * L_ + ts) * 128 + c8 * 8));
    if (rr < 64)
      *(int4*)&Xs[xswz(rr, c8 * 8)] = v;                 // tap0
    const int r1 = rr - 64;
    if (r1 >= 0)
      *(int4*)&Xs[xswz(r1, 120 + c8 * 8)] = v;           // tap1
  }
  for (int idx = tid; idx < 640; idx += 512) {
    const int c = idx % 10, trw = idx / 10;
    const int4 v = *(const int4*)(condb + ((size_t)(bb * L_ + t0 + trw) * M_ + c * 8));
    *(int4*)&Xs[xswz(trw, 240 + c * 8)] = v;
  }
  __syncthreads();

  const int lane = tid & 63;
  const int wv = tid >> 6;
  const int col = lane & 15;
  const int quad = lane >> 4;
  const int kq = quad * 8;

  // ---- GEMM1 ----
  f32x4 acc[4][2];
#pragma unroll
  for (int a = 0; a < 4; ++a)
#pragma unroll
    for (int b = 0; b < 2; ++b) acc[a][b] = (f32x4)(0.f);
  __builtin_amdgcn_s_setprio(1);
#pragma unroll
  for (int ks = 0; ks < 10; ++ks) {
    bf16x8 av[4];
#pragma unroll
    for (int tf = 0; tf < 4; ++tf)
      av[tf] = *(const bf16x8*)&Xs[xswz(tf * 16 + col, ks * 32 + kq)];
#pragma unroll
    for (int ct = 0; ct < 2; ++ct) {
      const int cpt = ((ct == 0) ? wv : (wv + 8)) * 16 + col;
      bf16x8 b = *(const bf16x8*)(W1 + cpt * 320 + ks * 32 + kq);
#pragma unroll
      for (int tf = 0; tf < 4; ++tf)
        acc[tf][ct] = __builtin_amdgcn_mfma_f32_16x16x32_bf16(av[tf], b, acc[tf][ct], 0, 0, 0);
    }
  }
  __builtin_amdgcn_s_setprio(0);
  __syncthreads();

  // ---- gating -> Zs in tap0 bytes ----
  {
    const int ch = wv * 16 + col;
    if (ch < 120) {
      const float bf_ = bias1[ch];
      const float bg_ = bias1[128 + ch];
#pragma unroll
      for (int tf = 0; tf < 4; ++tf) {
#pragma unroll
        for (int reg = 0; reg < 4; ++reg) {
          float f = acc[tf][0][reg] + bf_;
          float g = acc[tf][1][reg] + bg_;
          f = fminf(fmaxf(f, -15.f), 15.f);
          g = fminf(fmaxf(g, -15.f), 15.f);
          const float ef = __expf(2.0f * f);
          const float th = (ef - 1.0f) * __builtin_amdgcn_rcpf(ef + 1.0f);
          const float eg = __expf(-g);
          const float sg = __builtin_amdgcn_rcpf(1.0f + eg);
          const int t = tf * 16 + quad * 4 + reg;
          Xs[xswz(t, ch)] = f2bf(th * sg);
        }
      }
    }
  }
  if (tid < 64)
    *(int4*)&Xs[xswz(tid, 240)] = make_int4(0, 0, 0, 0);
  __syncthreads();

  // ---- skips old-value prefetch ----
  const size_t srow = ((size_t)bb * L_ + t0) * 240;
  int4 sk0, sk1, sk2, sk3 = make_int4(0,0,0,0);
  { const int idx = tid;        const int row = idx / 30, j = idx - row * 30;
    sk0 = *(const int4*)(skips + srow + row * 240 + j * 8); }
  { const int idx = tid + 512;  const int row = idx / 30, j = idx - row * 30;
    sk1 = *(const int4*)(skips + srow + row * 240 + j * 8); }
  { const int idx = tid + 1024; const int row = idx / 30, j = idx - row * 30;
    sk2 = *(const int4*)(skips + srow + row * 240 + j * 8); }
  if (tid + 1536 < 1920) {
    const int idx = tid + 1536; const int row = idx / 30, j = idx - row * 30;
    sk3 = *(const int4*)(skips + srow + row * 240 + j * 8); }

  // ---- GEMM2: skip tiles only ----
  f32x4 acc2[4][2];
#pragma unroll
  for (int a = 0; a < 4; ++a)
#pragma unroll
    for (int b = 0; b < 2; ++b) acc2[a][b] = (f32x4)(0.f);
  __builtin_amdgcn_s_setprio(1);
#pragma unroll
  for (int ks = 0; ks < 4; ++ks) {
    const int ko = ks * 32 + kq;
    const int kz = (ko >= 120) ? (ko + 120) : ko;
    bf16x8 av[4];
#pragma unroll
    for (int tf = 0; tf < 4; ++tf)
      av[tf] = *(const bf16x8*)&Xs[xswz(tf * 16 + col, kz)];
#pragma unroll
    for (int st = 0; st < 2; ++st) {
      const int tile = wv * 2 + st;
      if (tile < 15) {
        bf16x8 b = *(const bf16x8*)(W2 + (tile * 16 + col) * 128 + ks * 32 + kq);
#pragma unroll
        for (int tf = 0; tf < 4; ++tf)
          acc2[tf][st] = __builtin_amdgcn_mfma_f32_16x16x32_bf16(av[tf], b, acc2[tf][st], 0, 0, 0);
      }
    }
  }
  __builtin_amdgcn_s_setprio(0);
  __syncthreads();   // all Zs reads done -> SG overlay legal

  // ---- SG stage (swizzled, stride 256); zero pad cols 240..255 ----
  short* SG = Xs;
#pragma unroll
  for (int st = 0; st < 2; ++st) {
    const int tile = wv * 2 + st;
    if (tile < 15) {
      const int s = tile * 16 + col;
      const float b2 = bias2[s];
#pragma unroll
      for (int tf = 0; tf < 4; ++tf)
#pragma unroll
        for (int reg = 0; reg < 4; ++reg)
          SG[sswz(tf * 16 + quad * 4 + reg, s)] = f2bf(acc2[tf][st][reg] + b2);
    }
  }
  if (tid < 128) {
    const int row = tid >> 1, g = tid & 1;
    *(int4*)&SG[sswz(row, 240 + g * 8)] = make_int4(0, 0, 0, 0);
  }
  __syncthreads();

  // ---- in-place RMW + relu (swizzled) ----
#pragma unroll
  for (int it = 0; it < 4; ++it) {
    const int idx = tid + it * 512;
    if (idx < 1920) {
      const int row = idx / 30;
      const int j = idx - row * 30;
      short* lp = &SG[sswz(row, j * 8)];
      int4 sv = *(const int4*)lp;
      const unsigned short* svp = (const unsigned short*)&sv;
      const int4 ov = (it == 0) ? sk0 : (it == 1) ? sk1 : (it == 2) ? sk2 : sk3;
      const unsigned short* ovp = (const unsigned short*)&ov;
      int4 res;
      unsigned short* rp = (unsigned short*)&res;
#pragma unroll
      for (int e = 0; e < 8; ++e)
        rp[e] = (unsigned short)f2bf(fmaxf(bf2f(svp[e]) + bf2f(ovp[e]), 0.0f));
      *(int4*)lp = res;
    }
  }
  __syncthreads();

  // ---- h1 GEMM (K=256) ----
  f32x4 acc1[4][2];
#pragma unroll
  for (int a = 0; a < 4; ++a)
#pragma unroll
    for (int b = 0; b < 2; ++b) acc1[a][b] = (f32x4)(0.f);
  __builtin_amdgcn_s_setprio(1);
#pragma unroll
  for (int ks = 0; ks < 8; ++ks) {
    bf16x8 av[4];
#pragma unroll
    for (int tf = 0; tf < 4; ++tf)
      av[tf] = *(const bf16x8*)&SG[sswz(tf * 16 + col, ks * 32 + kq)];
#pragma unroll
    for (int ct = 0; ct < 2; ++ct) {
      bf16x8 b = *(const bf16x8*)(Wh1 + ((wv * 2 + ct) * 16 + col) * 256 + ks * 32 + kq);
#pragma unroll
      for (int tf = 0; tf < 4; ++tf)
        acc1[tf][ct] = __builtin_amdgcn_mfma_f32_16x16x32_bf16(av[tf], b, acc1[tf][ct], 0, 0, 0);
    }
  }
  __builtin_amdgcn_s_setprio(0);
  __syncthreads();   // SG reads done -> H overlay legal

#pragma unroll
  for (int ct = 0; ct < 2; ++ct) {
    const int q = (wv * 2 + ct) * 16 + col;
    const float b1 = bh1[q];
#pragma unroll
    for (int tf = 0; tf < 4; ++tf)
#pragma unroll
      for (int reg = 0; reg < 4; ++reg)
        SG[sswz(tf * 16 + quad * 4 + reg, q)] = f2bf(fmaxf(acc1[tf][ct][reg] + b1, 0.0f));
  }
  __syncthreads();

  // ---- h2 GEMM (K=256) -> out ----
  f32x4 acc2h[4][2];
#pragma unroll
  for (int a = 0; a < 4; ++a)
#pragma unroll
    for (int b = 0; b < 2; ++b) acc2h[a][b] = (f32x4)(0.f);
  __builtin_amdgcn_s_setprio(1);
#pragma unroll
  for (int ks = 0; ks < 8; ++ks) {
    bf16x8 av[4];
#pragma unroll
    for (int tf = 0; tf < 4; ++tf)
      av[tf] = *(const bf16x8*)&SG[sswz(tf * 16 + col, ks * 32 + kq)];
#pragma unroll
    for (int ct = 0; ct < 2; ++ct) {
      bf16x8 b = *(const bf16x8*)(Wh2 + ((wv * 2 + ct) * 16 + col) * 256 + ks * 32 + kq);
#pragma unroll
      for (int tf = 0; tf < 4; ++tf)
        acc2h[tf][ct] = __builtin_amdgcn_mfma_f32_16x16x32_bf16(av[tf], b, acc2h[tf][ct], 0, 0, 0);
    }
  }
  __builtin_amdgcn_s_setprio(0);
#pragma unroll
  for (int ct = 0; ct < 2; ++ct) {
    const int q = (wv * 2 + ct) * 16 + col;
    const float b2 = bh2[q];
#pragma unroll
    for (int tf = 0; tf < 4; ++tf) {
      const int tg0 = t0 + tf * 16 + quad * 4;
      float4 o = make_float4(acc2h[tf][ct][0] + b2, acc2h[tf][ct][1] + b2,
                             acc2h[tf][ct][2] + b2, acc2h[tf][ct][3] + b2);
      *(float4*)(out + ((size_t)(bb * Q_ + q)) * L_ + tg0) = o;
    }
  }
}

// ---------------------------------------------------------------------------
extern "C" void kernel_launch(void* const* d_in, const int* in_sizes, int n_in,
                              void* d_out, int out_size, void* d_ws, size_t ws_size,
                              hipStream_t stream) {
  const float* wav    = (const float*)d_in[0];
  const float* mel    = (const float*)d_in[1];
  const float* w_up   = (const float*)d_in[2];
  const float* b_up   = (const float*)d_in[3];
  const float* w_in   = (const float*)d_in[4];
  const float* b_in   = (const float*)d_in[5];
  const float* w_gate = (const float*)d_in[6];
  const float* b_gate = (const float*)d_in[7];
  const float* w_cond = (const float*)d_in[8];
  const float* b_cond = (const float*)d_in[9];
  const float* w_res  = (const float*)d_in[10];
  const float* b_res  = (const float*)d_in[11];
  const float* w_skip = (const float*)d_in[12];
  const float* b_skip = (const float*)d_in[13];
  const float* w_h1   = (const float*)d_in[14];
  const float* b_h1   = (const float*)d_in[15];
  const float* w_h2   = (const float*)d_in[16];
  const float* b_h2   = (const float*)d_in[17];
  float* out = (float*)d_out;

  char* w = (char*)d_ws;
  short* condb   = (short*)w;                 w += (size_t)B_ * L_ * M_ * 2;
  short* res0    = (short*)w;                 w += (size_t)B_ * L_ * 128 * 2;
  short* res1    = (short*)w;                 w += (size_t)B_ * L_ * 128 * 2;
  unsigned short* skips = (unsigned short*)w; w += (size_t)B_ * L_ * 240 * 2;
  short* W1p     = (short*)w;                 w += (size_t)16 * 256 * 320 * 2;
  short* W2p     = (short*)w;                 w += (size_t)16 * 384 * 128 * 2;
  short* Wh1p    = (short*)w;                 w += (size_t)256 * 256 * 2;
  short* Wh2p    = (short*)w;                 w += (size_t)256 * 256 * 2;
  float* bias1p  = (float*)w;                 w += (size_t)16 * 256 * 4;
  float* bias2p  = (float*)w;                 w += (size_t)16 * 384 * 4;
  short* melT    = (short*)w;                 w += (size_t)B_ * TMEL * M_ * 2;
  // Wup (13.1 MB) overlays skips: consumed before first block kernel.
  short* Wup = (short*)skips;

  prep_all_kernel<<<10103, 256, 0, stream>>>(
      w_gate, w_cond, w_skip, w_res, w_h1, w_h2,
      b_gate, b_cond, b_skip, b_res, mel, w_up,
      W1p, W2p, Wh1p, Wh2p, bias1p, bias2p, melT, Wup);

  dim3 ugrid(256, 4);
  upsample_mfma_kernel<<<ugrid, 256, 0, stream>>>(melT, Wup, b_up, condb);

  dim3 bgrid(NTILE, B_);
  for (int i = 0; i < NB_ - 1; ++i) {
    const int d = 1 << (i & 7);
    const short* rin  = (i & 1) ? res1 : res0;   // layer 0: unused (from wav)
    short*       rout = (i & 1) ? res0 : res1;
    block_mfma_kernel<<<bgrid, 512, 0, stream>>>(
        rin, rout, skips, condb, wav, w_in, b_in,
        W1p + (size_t)i * 256 * 320, W2p + (size_t)i * 384 * 128,
        bias1p + i * 256, bias2p + i * 384,
        d, (i == 0) ? 1 : 0);
  }
  // layer 15 (d=128, reads res1) fused with head
  block_mfma_last_kernel<<<bgrid, 512, 0, stream>>>(
      res1, skips, condb,
      W1p + (size_t)15 * 256 * 320, W2p + (size_t)15 * 384 * 128,
      bias1p + 15 * 256, bias2p + 15 * 384,
      Wh1p, Wh2p, b_h1, b_h2, out);
}